// Round 3
// baseline (662.353 us; speedup 1.0000x reference)
//
#include <hip/hip_runtime.h>
#include <hip/hip_bf16.h>

#define D 128
#define EPSV 1e-5f

static inline int cdiv(int a, int b) { return (a + b - 1) / b; }

// ---------------- edge preprocessing (fully deterministic) ----------------

__global__ void hist_kernel(const int* __restrict__ col, int* __restrict__ cnt, int E_) {
    int e = blockIdx.x * blockDim.x + threadIdx.x;
    if (e >= E_) return;
    atomicAdd(&cnt[col[e]], 1);  // int atomics: result order-independent
}

// 3-kernel exclusive scan over cnt[N] (chunk = 1024)
__global__ void scan_chunk_sums(const int* __restrict__ cnt, int* __restrict__ bsum, int n) {
    __shared__ int sm[1024];
    int i = blockIdx.x * 1024 + threadIdx.x;
    sm[threadIdx.x] = (i < n) ? cnt[i] : 0;
    __syncthreads();
    for (int off = 512; off > 0; off >>= 1) {
        if (threadIdx.x < off) sm[threadIdx.x] += sm[threadIdx.x + off];
        __syncthreads();
    }
    if (threadIdx.x == 0) bsum[blockIdx.x] = sm[0];
}

__global__ void scan_tops(const int* __restrict__ bsum, int* __restrict__ bo, int nb,
                          int* __restrict__ offs, int n, int E_) {
    if (threadIdx.x == 0 && blockIdx.x == 0) {
        int run = 0;
        for (int b = 0; b < nb; ++b) { bo[b] = run; run += bsum[b]; }
        offs[n] = E_;
    }
}

__global__ void scan_final(const int* __restrict__ cnt, const int* __restrict__ bo,
                           int* __restrict__ offs, int* __restrict__ cursor, int n) {
    __shared__ int sm[1024];
    int tid = threadIdx.x;
    int i = blockIdx.x * 1024 + tid;
    int v = (i < n) ? cnt[i] : 0;
    sm[tid] = v;
    __syncthreads();
    for (int off = 1; off < 1024; off <<= 1) {
        int t = (tid >= off) ? sm[tid - off] : 0;
        __syncthreads();
        sm[tid] += t;
        __syncthreads();
    }
    if (i < n) {
        int excl = sm[tid] - v + bo[blockIdx.x];
        offs[i] = excl;
        cursor[i] = excl;
    }
}

// scatter edge ids into CSR slots (placement order arbitrary; sorted next)
__global__ void scatter_eid(const int* __restrict__ col, int* __restrict__ cursor,
                            int* __restrict__ eid, int E_) {
    int e = blockIdx.x * blockDim.x + threadIdx.x;
    if (e >= E_) return;
    int p = atomicAdd(&cursor[col[e]], 1);
    eid[p] = e;
}

// canonicalize: per-node insertion sort of edge ids (ascending), then
// deterministic deg = sum(ea) in sorted order, dis = rsqrt guard.
__global__ void sort_deg_kernel(int* __restrict__ eid, const int* __restrict__ offs,
                                const float* __restrict__ ea, float* __restrict__ dis, int n) {
    int i = blockIdx.x * blockDim.x + threadIdx.x;
    if (i >= n) return;
    int p0 = offs[i], p1 = offs[i + 1];
    for (int a = p0 + 1; a < p1; ++a) {
        int key = eid[a];
        int b = a - 1;
        while (b >= p0 && eid[b] > key) { eid[b + 1] = eid[b]; --b; }
        eid[b + 1] = key;
    }
    float dg = 0.f;
    for (int p = p0; p < p1; ++p) dg += ea[eid[p]];
    dis[i] = dg > 0.f ? rsqrtf(fmaxf(dg, EPSV)) : 0.f;
}

// pack (src_row, norm_weight) into int2 so agg does one 8B load per edge
__global__ void fill_csr(const int* __restrict__ eid, const int* __restrict__ row,
                         const int* __restrict__ col, const float* __restrict__ ea,
                         const float* __restrict__ dis, int2* __restrict__ csr, int E_) {
    int p = blockIdx.x * blockDim.x + threadIdx.x;
    if (p >= E_) return;
    int e = eid[p];
    int r = row[e], c = col[e];
    float w = dis[r] * ea[e] * dis[c];
    csr[p] = make_int2(r, __float_as_int(w));
}

// ---------------- batch norm (deterministic partials) ----------------
// 256 threads = 8 rows x 32 lanes (float4 each); LDS tree; block partial to
// its own slot, reduced deterministically in bn_reduce.

template <bool GATHER>
__global__ __launch_bounds__(256) void bn_stats(const float* __restrict__ src,
                                                const int* __restrict__ idx,
                                                float4* __restrict__ pS4,
                                                float4* __restrict__ pQ4, int n) {
    int sub = threadIdx.x >> 5;
    int q = threadIdx.x & 31;
    float4 s = make_float4(0, 0, 0, 0), s2 = make_float4(0, 0, 0, 0);
    for (int i = blockIdx.x * 8 + sub; i < n; i += gridDim.x * 8) {
        int r = GATHER ? idx[i] : i;
        float4 v = *(const float4*)&src[(long)r * D + q * 4];
        s.x += v.x; s.y += v.y; s.z += v.z; s.w += v.w;
        s2.x += v.x * v.x; s2.y += v.y * v.y; s2.z += v.z * v.z; s2.w += v.w * v.w;
    }
    __shared__ float4 redA[256], redB[256];
    redA[threadIdx.x] = s;
    redB[threadIdx.x] = s2;
    __syncthreads();
    for (int off = 128; off >= 32; off >>= 1) {
        if (threadIdx.x < off) {
            float4 a = redA[threadIdx.x + off], b = redB[threadIdx.x + off];
            redA[threadIdx.x].x += a.x; redA[threadIdx.x].y += a.y;
            redA[threadIdx.x].z += a.z; redA[threadIdx.x].w += a.w;
            redB[threadIdx.x].x += b.x; redB[threadIdx.x].y += b.y;
            redB[threadIdx.x].z += b.z; redB[threadIdx.x].w += b.w;
        }
        __syncthreads();
    }
    if (threadIdx.x < 32) {
        pS4[blockIdx.x * 32 + q] = redA[threadIdx.x];
        pQ4[blockIdx.x * 32 + q] = redB[threadIdx.x];
    }
}

__global__ void bn_reduce(const float* __restrict__ pS, const float* __restrict__ pQ, int nb,
                          const float* __restrict__ gamma, const float* __restrict__ beta,
                          float* __restrict__ scale, float* __restrict__ shift, float n) {
    int d = threadIdx.x;
    float s = 0.f, q = 0.f;
    for (int b = 0; b < nb; ++b) {
        s += pS[b * D + d];
        q += pQ[b * D + d];
    }
    float mean = s / n;
    float var = q / n - mean * mean;
    float rstd = rsqrtf(var + EPSV);
    float sc = gamma[d] * rstd;
    scale[d] = sc;
    shift[d] = beta[d] - mean * sc;
}

// ---------------- GEMM: h = (src*scale+shift) @ W ----------------
// 256 threads = 8 rowgroups x 32 colgroups, each thread a 4x4 micro-tile.

template <bool GATHER>
__global__ __launch_bounds__(256) void gemm_bn(const float* __restrict__ src,
                                               const int* __restrict__ idx,
                                               const float* __restrict__ scale,
                                               const float* __restrict__ shift,
                                               const float* __restrict__ W,
                                               float* __restrict__ out, int n) {
    __shared__ float xsT[128 * 36];  // [k][r], stride 36 keeps b128 16B-aligned
    int r0 = blockIdx.x * 32;
    int tid = threadIdx.x;
    for (int it = 0; it < 16; ++it) {
        int flat = it * 256 + tid;
        int r = flat >> 7;
        int k = flat & 127;
        int gr = r0 + r;
        float v = 0.f;
        if (gr < n) {
            int srow = GATHER ? idx[gr] : gr;
            v = src[(long)srow * D + k] * scale[k] + shift[k];
        }
        xsT[k * 36 + r] = v;
    }
    __syncthreads();
    int cg = tid & 31;   // cols cg*4..cg*4+3
    int rg = tid >> 5;   // rows rg*4..rg*4+3
    float acc[4][4];
#pragma unroll
    for (int j = 0; j < 4; ++j)
#pragma unroll
        for (int q = 0; q < 4; ++q) acc[j][q] = 0.f;
    const float4* Wv = (const float4*)W;
#pragma unroll 4
    for (int k = 0; k < 128; ++k) {
        float4 wv = Wv[k * 32 + cg];
        float4 xv = *(const float4*)&xsT[k * 36 + rg * 4];
        acc[0][0] += xv.x * wv.x; acc[0][1] += xv.x * wv.y; acc[0][2] += xv.x * wv.z; acc[0][3] += xv.x * wv.w;
        acc[1][0] += xv.y * wv.x; acc[1][1] += xv.y * wv.y; acc[1][2] += xv.y * wv.z; acc[1][3] += xv.y * wv.w;
        acc[2][0] += xv.z * wv.x; acc[2][1] += xv.z * wv.y; acc[2][2] += xv.z * wv.z; acc[2][3] += xv.z * wv.w;
        acc[3][0] += xv.w * wv.x; acc[3][1] += xv.w * wv.y; acc[3][2] += xv.w * wv.z; acc[3][3] += xv.w * wv.w;
    }
#pragma unroll
    for (int j = 0; j < 4; ++j) {
        int gr = r0 + rg * 4 + j;
        if (gr < n) {
            *(float4*)&out[(long)gr * D + cg * 4] =
                make_float4(acc[j][0], acc[j][1], acc[j][2], acc[j][3]);
        }
    }
}

// ---------------- aggregation: x[i] = relu(b + sum_e w_e * h[row_e]) ----------------
// 1 node per wave (64 lanes x float2); 4 nodes per block; 4-edge unroll.

__global__ __launch_bounds__(256) void agg_kernel(const float2* __restrict__ h2,
                                                  const int2* __restrict__ csr,
                                                  const int* __restrict__ offs,
                                                  const float2* __restrict__ bias2,
                                                  float2* __restrict__ xout, int n) {
    int node = blockIdx.x * 4 + (threadIdx.x >> 6);
    int d = threadIdx.x & 63;
    if (node >= n) return;
    int p0 = offs[node], p1 = offs[node + 1];
    float2 acc = bias2[d];
    int p = p0;
    for (; p + 4 <= p1; p += 4) {
        int2 e0 = csr[p], e1 = csr[p + 1], e2 = csr[p + 2], e3 = csr[p + 3];
        float2 v0 = h2[(long)e0.x * 64 + d];
        float2 v1 = h2[(long)e1.x * 64 + d];
        float2 v2 = h2[(long)e2.x * 64 + d];
        float2 v3 = h2[(long)e3.x * 64 + d];
        float w0 = __int_as_float(e0.y), w1 = __int_as_float(e1.y);
        float w2 = __int_as_float(e2.y), w3 = __int_as_float(e3.y);
        acc.x += w0 * v0.x; acc.y += w0 * v0.y;
        acc.x += w1 * v1.x; acc.y += w1 * v1.y;
        acc.x += w2 * v2.x; acc.y += w2 * v2.y;
        acc.x += w3 * v3.x; acc.y += w3 * v3.y;
    }
    for (; p < p1; ++p) {
        int2 e = csr[p];
        float2 v = h2[(long)e.x * 64 + d];
        float w = __int_as_float(e.y);
        acc.x += w * v.x; acc.y += w * v.y;
    }
    xout[(long)node * 64 + d] = make_float2(fmaxf(acc.x, 0.f), fmaxf(acc.y, 0.f));
}

// ---------------- segment boundaries + softmax pooling ----------------

__global__ void bounds_kernel(const int* __restrict__ batch, int* __restrict__ start, int n,
                              int G_) {
    int g = blockIdx.x * blockDim.x + threadIdx.x;
    if (g > G_) return;
    int lo = 0, hi = n;
    while (lo < hi) {
        int mid = (lo + hi) >> 1;
        if (batch[mid] < g) lo = mid + 1;
        else hi = mid;
    }
    start[g] = lo;
}

__global__ __launch_bounds__(512) void pool_kernel(const float* __restrict__ tfidf,
                                                   const int* __restrict__ start,
                                                   const float* __restrict__ x,
                                                   float* __restrict__ out) {
    int g = blockIdx.x;
    int s0 = start[g], s1 = start[g + 1];
    int tid = threadIdx.x;
    int d = tid & 127, sub = tid >> 7;  // 4-way node split
    __shared__ float red[512];
    // pass 1: segment max of tfidf
    float m = -1e30f;
    for (int i = s0 + tid; i < s1; i += 512) m = fmaxf(m, tfidf[i]);
    red[tid] = m;
    __syncthreads();
    for (int off = 256; off > 0; off >>= 1) {
        if (tid < off) red[tid] = fmaxf(red[tid], red[tid + off]);
        __syncthreads();
    }
    m = red[0];
    __syncthreads();
    // pass 2: sum of exp
    float s = 0.f;
    for (int i = s0 + tid; i < s1; i += 512) s += __expf(tfidf[i] - m);
    red[tid] = s;
    __syncthreads();
    for (int off = 256; off > 0; off >>= 1) {
        if (tid < off) red[tid] += red[tid + off];
        __syncthreads();
    }
    s = red[0];
    __syncthreads();
    // pass 3: weighted feature sum, 4 nodes in flight
    float acc = 0.f;
    for (int i = s0 + sub; i < s1; i += 4) acc += __expf(tfidf[i] - m) * x[(long)i * D + d];
    red[tid] = acc;
    __syncthreads();
    if (tid < 128) {
        float a = red[d] + red[128 + d] + red[256 + d] + red[384 + d];
        out[g * D + d] = (s1 > s0) ? a / s : 0.f;
    }
}

// ---------------- launch ----------------

extern "C" void kernel_launch(void* const* d_in, const int* in_sizes, int n_in, void* d_out,
                              int out_size, void* d_ws, size_t ws_size, hipStream_t stream) {
    const int N = in_sizes[0];
    const int E = in_sizes[4];
    const int G = out_size / D;
    const int BN_GRID = 512;

    const int* x_index = (const int*)d_in[0];
    const float* tfidf = (const float*)d_in[1];
    const int* ei_row = (const int*)d_in[2];
    const int* ei_col = ei_row + E;
    const int* batch = (const int*)d_in[3];
    const float* edge_attr = (const float*)d_in[4];
    const float* emb = (const float*)d_in[5];
    const float* gamma1 = (const float*)d_in[6];
    const float* beta1 = (const float*)d_in[7];
    const float* W1 = (const float*)d_in[8];
    const float* b1 = (const float*)d_in[9];
    const float* gamma2 = (const float*)d_in[10];
    const float* beta2 = (const float*)d_in[11];
    const float* W2 = (const float*)d_in[12];
    const float* b2 = (const float*)d_in[13];
    float* out = (float*)d_out;

    // ---- workspace carve (256B aligned) ----
    size_t off = 0;
    char* base = (char*)d_ws;
    auto carve = [&](size_t bytes) -> void* {
        void* p = base + off;
        off = (off + bytes + 255) & ~(size_t)255;
        return p;
    };
    float* bufA = (float*)carve((size_t)N * D * 4);  // h (gemm output)
    float* bufB = (float*)carve((size_t)N * D * 4);  // x (layer output)
    int* eid = (int*)carve((size_t)E * 4);           // CSR edge ids
    int2* csr = (int2*)carve((size_t)E * 8);         // packed (row, w)
    int* cnt = (int*)carve((size_t)N * 4);           // zeroed each launch
    float* dis = (float*)carve((size_t)N * 4);
    int* offs = (int*)carve((size_t)(N + 1) * 4);
    int* cursor = (int*)carve((size_t)N * 4);
    int* bsum = (int*)carve(64 * 4);
    int* bo = (int*)carve(64 * 4);
    int* start = (int*)carve((size_t)(G + 1) * 4);
    float* scale1 = (float*)carve(D * 4);
    float* shift1 = (float*)carve(D * 4);
    float* scale2 = (float*)carve(D * 4);
    float* shift2 = (float*)carve(D * 4);
    float* pS = (float*)carve((size_t)BN_GRID * D * 4);
    float* pQ = (float*)carve((size_t)BN_GRID * D * 4);
    (void)ws_size;
    (void)n_in;

    hipMemsetAsync(cnt, 0, (size_t)N * 4, stream);

    // ---- edge preprocessing: CSR (deterministic; shared by both layers) ----
    hist_kernel<<<cdiv(E, 256), 256, 0, stream>>>(ei_col, cnt, E);
    int nb = cdiv(N, 1024);
    scan_chunk_sums<<<nb, 1024, 0, stream>>>(cnt, bsum, N);
    scan_tops<<<1, 1, 0, stream>>>(bsum, bo, nb, offs, N, E);
    scan_final<<<nb, 1024, 0, stream>>>(cnt, bo, offs, cursor, N);
    scatter_eid<<<cdiv(E, 256), 256, 0, stream>>>(ei_col, cursor, eid, E);
    sort_deg_kernel<<<cdiv(N, 256), 256, 0, stream>>>(eid, offs, edge_attr, dis, N);
    fill_csr<<<cdiv(E, 256), 256, 0, stream>>>(eid, ei_row, ei_col, edge_attr, dis, csr, E);

    // ---- layer 1 ----
    bn_stats<true><<<BN_GRID, 256, 0, stream>>>(emb, x_index, (float4*)pS, (float4*)pQ, N);
    bn_reduce<<<1, 128, 0, stream>>>(pS, pQ, BN_GRID, gamma1, beta1, scale1, shift1, (float)N);
    gemm_bn<true><<<cdiv(N, 32), 256, 0, stream>>>(emb, x_index, scale1, shift1, W1, bufA, N);
    agg_kernel<<<cdiv(N, 4), 256, 0, stream>>>((const float2*)bufA, csr, offs,
                                               (const float2*)b1, (float2*)bufB, N);

    // ---- layer 2 ----
    bn_stats<false><<<BN_GRID, 256, 0, stream>>>(bufB, nullptr, (float4*)pS, (float4*)pQ, N);
    bn_reduce<<<1, 128, 0, stream>>>(pS, pQ, BN_GRID, gamma2, beta2, scale2, shift2, (float)N);
    gemm_bn<false><<<cdiv(N, 32), 256, 0, stream>>>(bufB, nullptr, scale2, shift2, W2, bufA, N);
    agg_kernel<<<cdiv(N, 4), 256, 0, stream>>>((const float2*)bufA, csr, offs,
                                               (const float2*)b2, (float2*)bufB, N);

    // ---- softmax pooling ----
    bounds_kernel<<<cdiv(G + 1, 256), 256, 0, stream>>>(batch, start, N, G);
    pool_kernel<<<G, 512, 0, stream>>>(tfidf, start, bufB, out);
}

// Round 4
// 419.086 us; speedup vs baseline: 1.5805x; 1.5805x over previous
//
#include <hip/hip_runtime.h>
#include <hip/hip_bf16.h>

#define D 128
#define EPSV 1e-5f

static inline int cdiv(int a, int b) { return (a + b - 1) / b; }

// ---------------- edge preprocessing (fully deterministic) ----------------

__global__ void hist_kernel(const int* __restrict__ col, int* __restrict__ cnt, int E_) {
    int e = blockIdx.x * blockDim.x + threadIdx.x;
    if (e >= E_) return;
    atomicAdd(&cnt[col[e]], 1);  // int atomics: result order-independent
}

// 3-kernel exclusive scan over cnt[N] (chunk = 1024)
__global__ void scan_chunk_sums(const int* __restrict__ cnt, int* __restrict__ bsum, int n) {
    __shared__ int sm[1024];
    int i = blockIdx.x * 1024 + threadIdx.x;
    sm[threadIdx.x] = (i < n) ? cnt[i] : 0;
    __syncthreads();
    for (int off = 512; off > 0; off >>= 1) {
        if (threadIdx.x < off) sm[threadIdx.x] += sm[threadIdx.x + off];
        __syncthreads();
    }
    if (threadIdx.x == 0) bsum[blockIdx.x] = sm[0];
}

__global__ void scan_tops(const int* __restrict__ bsum, int* __restrict__ bo, int nb,
                          int* __restrict__ offs, int n, int E_) {
    if (threadIdx.x == 0 && blockIdx.x == 0) {
        int run = 0;
        for (int b = 0; b < nb; ++b) { bo[b] = run; run += bsum[b]; }
        offs[n] = E_;
    }
}

__global__ void scan_final(const int* __restrict__ cnt, const int* __restrict__ bo,
                           int* __restrict__ offs, int* __restrict__ cursor, int n) {
    __shared__ int sm[1024];
    int tid = threadIdx.x;
    int i = blockIdx.x * 1024 + tid;
    int v = (i < n) ? cnt[i] : 0;
    sm[tid] = v;
    __syncthreads();
    for (int off = 1; off < 1024; off <<= 1) {
        int t = (tid >= off) ? sm[tid - off] : 0;
        __syncthreads();
        sm[tid] += t;
        __syncthreads();
    }
    if (i < n) {
        int excl = sm[tid] - v + bo[blockIdx.x];
        offs[i] = excl;
        cursor[i] = excl;
    }
}

// scatter edge ids into CSR slots (placement order arbitrary; sorted next)
__global__ void scatter_eid(const int* __restrict__ col, int* __restrict__ cursor,
                            int* __restrict__ eid, int E_) {
    int e = blockIdx.x * blockDim.x + threadIdx.x;
    if (e >= E_) return;
    int p = atomicAdd(&cursor[col[e]], 1);
    eid[p] = e;
}

// canonicalize: per-node insertion sort of edge ids (ascending), then
// deterministic deg = sum(ea) in sorted order, dis = rsqrt guard.
__global__ void sort_deg_kernel(int* __restrict__ eid, const int* __restrict__ offs,
                                const float* __restrict__ ea, float* __restrict__ dis, int n) {
    int i = blockIdx.x * blockDim.x + threadIdx.x;
    if (i >= n) return;
    int p0 = offs[i], p1 = offs[i + 1];
    for (int a = p0 + 1; a < p1; ++a) {
        int key = eid[a];
        int b = a - 1;
        while (b >= p0 && eid[b] > key) { eid[b + 1] = eid[b]; --b; }
        eid[b + 1] = key;
    }
    float dg = 0.f;
    for (int p = p0; p < p1; ++p) dg += ea[eid[p]];
    dis[i] = dg > 0.f ? rsqrtf(fmaxf(dg, EPSV)) : 0.f;
}

// pack (src_row, norm_weight) into int2 so agg does one 8B load per edge
__global__ void fill_csr(const int* __restrict__ eid, const int* __restrict__ row,
                         const int* __restrict__ col, const float* __restrict__ ea,
                         const float* __restrict__ dis, int2* __restrict__ csr, int E_) {
    int p = blockIdx.x * blockDim.x + threadIdx.x;
    if (p >= E_) return;
    int e = eid[p];
    int r = row[e], c = col[e];
    float w = dis[r] * ea[e] * dis[c];
    csr[p] = make_int2(r, __float_as_int(w));
}

// ---------------- batch norm (deterministic partials) ----------------
// 256 threads = 8 rows x 32 lanes (float4 each); LDS tree; block partials
// written TRANSPOSED (pS[d*NB + block]) so bn_reduce reads coalesced.

template <bool GATHER>
__global__ __launch_bounds__(256) void bn_stats(const float* __restrict__ src,
                                                const int* __restrict__ idx,
                                                float* __restrict__ pS,
                                                float* __restrict__ pQ, int n, int NB) {
    int sub = threadIdx.x >> 5;
    int q = threadIdx.x & 31;
    float4 s = make_float4(0, 0, 0, 0), s2 = make_float4(0, 0, 0, 0);
    for (int i = blockIdx.x * 8 + sub; i < n; i += gridDim.x * 8) {
        int r = GATHER ? idx[i] : i;
        float4 v = *(const float4*)&src[(long)r * D + q * 4];
        s.x += v.x; s.y += v.y; s.z += v.z; s.w += v.w;
        s2.x += v.x * v.x; s2.y += v.y * v.y; s2.z += v.z * v.z; s2.w += v.w * v.w;
    }
    __shared__ float4 redA[256], redB[256];
    redA[threadIdx.x] = s;
    redB[threadIdx.x] = s2;
    __syncthreads();
    for (int off = 128; off >= 32; off >>= 1) {
        if (threadIdx.x < off) {
            float4 a = redA[threadIdx.x + off], b = redB[threadIdx.x + off];
            redA[threadIdx.x].x += a.x; redA[threadIdx.x].y += a.y;
            redA[threadIdx.x].z += a.z; redA[threadIdx.x].w += a.w;
            redB[threadIdx.x].x += b.x; redB[threadIdx.x].y += b.y;
            redB[threadIdx.x].z += b.z; redB[threadIdx.x].w += b.w;
        }
        __syncthreads();
    }
    if (threadIdx.x < 32) {
        float4 a = redA[threadIdx.x], b = redB[threadIdx.x];
        int bofs = blockIdx.x;
        pS[(q * 4 + 0) * NB + bofs] = a.x;
        pS[(q * 4 + 1) * NB + bofs] = a.y;
        pS[(q * 4 + 2) * NB + bofs] = a.z;
        pS[(q * 4 + 3) * NB + bofs] = a.w;
        pQ[(q * 4 + 0) * NB + bofs] = b.x;
        pQ[(q * 4 + 1) * NB + bofs] = b.y;
        pQ[(q * 4 + 2) * NB + bofs] = b.z;
        pQ[(q * 4 + 3) * NB + bofs] = b.w;
    }
}

// one block per feature d; coalesced reads of pS[d*NB..], LDS tree reduce.
__global__ __launch_bounds__(256) void bn_reduce(const float* __restrict__ pS,
                                                 const float* __restrict__ pQ, int nb,
                                                 const float* __restrict__ gamma,
                                                 const float* __restrict__ beta,
                                                 float* __restrict__ scale,
                                                 float* __restrict__ shift, float n) {
    int d = blockIdx.x;
    int tid = threadIdx.x;
    float s = 0.f, q = 0.f;
    for (int b = tid; b < nb; b += 256) {
        s += pS[d * nb + b];
        q += pQ[d * nb + b];
    }
    __shared__ float smS[256], smQ[256];
    smS[tid] = s;
    smQ[tid] = q;
    __syncthreads();
    for (int off = 128; off > 0; off >>= 1) {
        if (tid < off) {
            smS[tid] += smS[tid + off];
            smQ[tid] += smQ[tid + off];
        }
        __syncthreads();
    }
    if (tid == 0) {
        float mean = smS[0] / n;
        float var = smQ[0] / n - mean * mean;
        float rstd = rsqrtf(var + EPSV);
        float sc = gamma[d] * rstd;
        scale[d] = sc;
        shift[d] = beta[d] - mean * sc;
    }
}

// ---------------- GEMM: h = (src*scale+shift) @ W ----------------
// 256 threads = 8 rowgroups x 32 colgroups, each thread a 4x4 micro-tile.

template <bool GATHER>
__global__ __launch_bounds__(256) void gemm_bn(const float* __restrict__ src,
                                               const int* __restrict__ idx,
                                               const float* __restrict__ scale,
                                               const float* __restrict__ shift,
                                               const float* __restrict__ W,
                                               float* __restrict__ out, int n) {
    __shared__ float xsT[128 * 36];  // [k][r], stride 36 keeps b128 16B-aligned
    int r0 = blockIdx.x * 32;
    int tid = threadIdx.x;
    for (int it = 0; it < 16; ++it) {
        int flat = it * 256 + tid;
        int r = flat >> 7;
        int k = flat & 127;
        int gr = r0 + r;
        float v = 0.f;
        if (gr < n) {
            int srow = GATHER ? idx[gr] : gr;
            v = src[(long)srow * D + k] * scale[k] + shift[k];
        }
        xsT[k * 36 + r] = v;
    }
    __syncthreads();
    int cg = tid & 31;   // cols cg*4..cg*4+3
    int rg = tid >> 5;   // rows rg*4..rg*4+3
    float acc[4][4];
#pragma unroll
    for (int j = 0; j < 4; ++j)
#pragma unroll
        for (int q = 0; q < 4; ++q) acc[j][q] = 0.f;
    const float4* Wv = (const float4*)W;
#pragma unroll 4
    for (int k = 0; k < 128; ++k) {
        float4 wv = Wv[k * 32 + cg];
        float4 xv = *(const float4*)&xsT[k * 36 + rg * 4];
        acc[0][0] += xv.x * wv.x; acc[0][1] += xv.x * wv.y; acc[0][2] += xv.x * wv.z; acc[0][3] += xv.x * wv.w;
        acc[1][0] += xv.y * wv.x; acc[1][1] += xv.y * wv.y; acc[1][2] += xv.y * wv.z; acc[1][3] += xv.y * wv.w;
        acc[2][0] += xv.z * wv.x; acc[2][1] += xv.z * wv.y; acc[2][2] += xv.z * wv.z; acc[2][3] += xv.z * wv.w;
        acc[3][0] += xv.w * wv.x; acc[3][1] += xv.w * wv.y; acc[3][2] += xv.w * wv.z; acc[3][3] += xv.w * wv.w;
    }
#pragma unroll
    for (int j = 0; j < 4; ++j) {
        int gr = r0 + rg * 4 + j;
        if (gr < n) {
            *(float4*)&out[(long)gr * D + cg * 4] =
                make_float4(acc[j][0], acc[j][1], acc[j][2], acc[j][3]);
        }
    }
}

// ---------------- aggregation: x[i] = relu(b + sum_e w_e * h[row_e]) ----------------
// 1 node per wave (64 lanes x float2); 4 nodes per block; 4-edge unroll.

__global__ __launch_bounds__(256) void agg_kernel(const float2* __restrict__ h2,
                                                  const int2* __restrict__ csr,
                                                  const int* __restrict__ offs,
                                                  const float2* __restrict__ bias2,
                                                  float2* __restrict__ xout, int n) {
    int node = blockIdx.x * 4 + (threadIdx.x >> 6);
    int d = threadIdx.x & 63;
    if (node >= n) return;
    int p0 = offs[node], p1 = offs[node + 1];
    float2 acc = bias2[d];
    int p = p0;
    for (; p + 4 <= p1; p += 4) {
        int2 e0 = csr[p], e1 = csr[p + 1], e2 = csr[p + 2], e3 = csr[p + 3];
        float2 v0 = h2[(long)e0.x * 64 + d];
        float2 v1 = h2[(long)e1.x * 64 + d];
        float2 v2 = h2[(long)e2.x * 64 + d];
        float2 v3 = h2[(long)e3.x * 64 + d];
        float w0 = __int_as_float(e0.y), w1 = __int_as_float(e1.y);
        float w2 = __int_as_float(e2.y), w3 = __int_as_float(e3.y);
        acc.x += w0 * v0.x; acc.y += w0 * v0.y;
        acc.x += w1 * v1.x; acc.y += w1 * v1.y;
        acc.x += w2 * v2.x; acc.y += w2 * v2.y;
        acc.x += w3 * v3.x; acc.y += w3 * v3.y;
    }
    for (; p < p1; ++p) {
        int2 e = csr[p];
        float2 v = h2[(long)e.x * 64 + d];
        float w = __int_as_float(e.y);
        acc.x += w * v.x; acc.y += w * v.y;
    }
    xout[(long)node * 64 + d] = make_float2(fmaxf(acc.x, 0.f), fmaxf(acc.y, 0.f));
}

// ---------------- segment boundaries + softmax pooling ----------------

__global__ void bounds_kernel(const int* __restrict__ batch, int* __restrict__ start, int n,
                              int G_) {
    int g = blockIdx.x * blockDim.x + threadIdx.x;
    if (g > G_) return;
    int lo = 0, hi = n;
    while (lo < hi) {
        int mid = (lo + hi) >> 1;
        if (batch[mid] < g) lo = mid + 1;
        else hi = mid;
    }
    start[g] = lo;
}

__global__ __launch_bounds__(512) void pool_kernel(const float* __restrict__ tfidf,
                                                   const int* __restrict__ start,
                                                   const float* __restrict__ x,
                                                   float* __restrict__ out) {
    int g = blockIdx.x;
    int s0 = start[g], s1 = start[g + 1];
    int tid = threadIdx.x;
    int d = tid & 127, sub = tid >> 7;  // 4-way node split
    __shared__ float red[512];
    // pass 1: segment max of tfidf
    float m = -1e30f;
    for (int i = s0 + tid; i < s1; i += 512) m = fmaxf(m, tfidf[i]);
    red[tid] = m;
    __syncthreads();
    for (int off = 256; off > 0; off >>= 1) {
        if (tid < off) red[tid] = fmaxf(red[tid], red[tid + off]);
        __syncthreads();
    }
    m = red[0];
    __syncthreads();
    // pass 2: sum of exp
    float s = 0.f;
    for (int i = s0 + tid; i < s1; i += 512) s += __expf(tfidf[i] - m);
    red[tid] = s;
    __syncthreads();
    for (int off = 256; off > 0; off >>= 1) {
        if (tid < off) red[tid] += red[tid + off];
        __syncthreads();
    }
    s = red[0];
    __syncthreads();
    // pass 3: weighted feature sum, 4 nodes in flight
    float acc = 0.f;
    for (int i = s0 + sub; i < s1; i += 4) acc += __expf(tfidf[i] - m) * x[(long)i * D + d];
    red[tid] = acc;
    __syncthreads();
    if (tid < 128) {
        float a = red[d] + red[128 + d] + red[256 + d] + red[384 + d];
        out[g * D + d] = (s1 > s0) ? a / s : 0.f;
    }
}

// ---------------- launch ----------------

extern "C" void kernel_launch(void* const* d_in, const int* in_sizes, int n_in, void* d_out,
                              int out_size, void* d_ws, size_t ws_size, hipStream_t stream) {
    const int N = in_sizes[0];
    const int E = in_sizes[4];
    const int G = out_size / D;
    const int BN_GRID = 512;

    const int* x_index = (const int*)d_in[0];
    const float* tfidf = (const float*)d_in[1];
    const int* ei_row = (const int*)d_in[2];
    const int* ei_col = ei_row + E;
    const int* batch = (const int*)d_in[3];
    const float* edge_attr = (const float*)d_in[4];
    const float* emb = (const float*)d_in[5];
    const float* gamma1 = (const float*)d_in[6];
    const float* beta1 = (const float*)d_in[7];
    const float* W1 = (const float*)d_in[8];
    const float* b1 = (const float*)d_in[9];
    const float* gamma2 = (const float*)d_in[10];
    const float* beta2 = (const float*)d_in[11];
    const float* W2 = (const float*)d_in[12];
    const float* b2 = (const float*)d_in[13];
    float* out = (float*)d_out;

    // ---- workspace carve (256B aligned) ----
    size_t off = 0;
    char* base = (char*)d_ws;
    auto carve = [&](size_t bytes) -> void* {
        void* p = base + off;
        off = (off + bytes + 255) & ~(size_t)255;
        return p;
    };
    float* bufA = (float*)carve((size_t)N * D * 4);  // h (gemm output)
    float* bufB = (float*)carve((size_t)N * D * 4);  // x (layer output)
    int* eid = (int*)carve((size_t)E * 4);           // CSR edge ids
    int2* csr = (int2*)carve((size_t)E * 8);         // packed (row, w)
    int* cnt = (int*)carve((size_t)N * 4);           // zeroed each launch
    float* dis = (float*)carve((size_t)N * 4);
    int* offs = (int*)carve((size_t)(N + 1) * 4);
    int* cursor = (int*)carve((size_t)N * 4);
    int* bsum = (int*)carve(64 * 4);
    int* bo = (int*)carve(64 * 4);
    int* start = (int*)carve((size_t)(G + 1) * 4);
    float* scale1 = (float*)carve(D * 4);
    float* shift1 = (float*)carve(D * 4);
    float* scale2 = (float*)carve(D * 4);
    float* shift2 = (float*)carve(D * 4);
    float* pS = (float*)carve((size_t)BN_GRID * D * 4);
    float* pQ = (float*)carve((size_t)BN_GRID * D * 4);
    (void)ws_size;
    (void)n_in;

    hipMemsetAsync(cnt, 0, (size_t)N * 4, stream);

    // ---- edge preprocessing: CSR (deterministic; shared by both layers) ----
    hist_kernel<<<cdiv(E, 256), 256, 0, stream>>>(ei_col, cnt, E);
    int nb = cdiv(N, 1024);
    scan_chunk_sums<<<nb, 1024, 0, stream>>>(cnt, bsum, N);
    scan_tops<<<1, 1, 0, stream>>>(bsum, bo, nb, offs, N, E);
    scan_final<<<nb, 1024, 0, stream>>>(cnt, bo, offs, cursor, N);
    scatter_eid<<<cdiv(E, 256), 256, 0, stream>>>(ei_col, cursor, eid, E);
    sort_deg_kernel<<<cdiv(N, 256), 256, 0, stream>>>(eid, offs, edge_attr, dis, N);
    fill_csr<<<cdiv(E, 256), 256, 0, stream>>>(eid, ei_row, ei_col, edge_attr, dis, csr, E);

    // ---- layer 1 ----
    bn_stats<true><<<BN_GRID, 256, 0, stream>>>(emb, x_index, pS, pQ, N, BN_GRID);
    bn_reduce<<<D, 256, 0, stream>>>(pS, pQ, BN_GRID, gamma1, beta1, scale1, shift1, (float)N);
    gemm_bn<true><<<cdiv(N, 32), 256, 0, stream>>>(emb, x_index, scale1, shift1, W1, bufA, N);
    agg_kernel<<<cdiv(N, 4), 256, 0, stream>>>((const float2*)bufA, csr, offs,
                                               (const float2*)b1, (float2*)bufB, N);

    // ---- layer 2 ----
    bn_stats<false><<<BN_GRID, 256, 0, stream>>>(bufB, nullptr, pS, pQ, N, BN_GRID);
    bn_reduce<<<D, 256, 0, stream>>>(pS, pQ, BN_GRID, gamma2, beta2, scale2, shift2, (float)N);
    gemm_bn<false><<<cdiv(N, 32), 256, 0, stream>>>(bufB, nullptr, scale2, shift2, W2, bufA, N);
    agg_kernel<<<cdiv(N, 4), 256, 0, stream>>>((const float2*)bufA, csr, offs,
                                               (const float2*)b2, (float2*)bufB, N);

    // ---- softmax pooling ----
    bounds_kernel<<<cdiv(G + 1, 256), 256, 0, stream>>>(batch, start, N, G);
    pool_kernel<<<G, 512, 0, stream>>>(tfidf, start, bufB, out);
}

// Round 5
// 402.956 us; speedup vs baseline: 1.6437x; 1.0400x over previous
//
#include <hip/hip_runtime.h>
#include <hip/hip_bf16.h>

#define D 128
#define EPSV 1e-5f

static inline int cdiv(int a, int b) { return (a + b - 1) / b; }

// ---------------- edge preprocessing (fully deterministic) ----------------

__global__ void hist_kernel(const int* __restrict__ col, int* __restrict__ cnt, int E_) {
    int e = blockIdx.x * blockDim.x + threadIdx.x;
    if (e >= E_) return;
    atomicAdd(&cnt[col[e]], 1);  // int atomics: result order-independent
}

// scan over cnt[N] (chunk = 1024): block sums, then final scan (tops fused)
__global__ void scan_chunk_sums(const int* __restrict__ cnt, int* __restrict__ bsum, int n) {
    __shared__ int sm[1024];
    int i = blockIdx.x * 1024 + threadIdx.x;
    sm[threadIdx.x] = (i < n) ? cnt[i] : 0;
    __syncthreads();
    for (int off = 512; off > 0; off >>= 1) {
        if (threadIdx.x < off) sm[threadIdx.x] += sm[threadIdx.x + off];
        __syncthreads();
    }
    if (threadIdx.x == 0) bsum[blockIdx.x] = sm[0];
}

// final scan; block offset computed in-block from bsum (scan_tops fused)
__global__ void scan_final(const int* __restrict__ cnt, const int* __restrict__ bsum, int nbk,
                           int* __restrict__ offs, int* __restrict__ cursor, int n, int E_) {
    __shared__ int sm[1024];
    __shared__ int sbo;
    int tid = threadIdx.x;
    // parallel reduce of bsum[0..blockIdx.x) into sbo
    int bv = (tid < nbk && tid < blockIdx.x) ? bsum[tid] : 0;
    sm[tid] = bv;
    __syncthreads();
    for (int off = 512; off > 0; off >>= 1) {
        if (tid < off) sm[tid] += sm[tid + off];
        __syncthreads();
    }
    if (tid == 0) {
        sbo = sm[0];
        if (blockIdx.x == 0) offs[n] = E_;
    }
    __syncthreads();
    int i = blockIdx.x * 1024 + tid;
    int v = (i < n) ? cnt[i] : 0;
    sm[tid] = v;
    __syncthreads();
    for (int off = 1; off < 1024; off <<= 1) {
        int t = (tid >= off) ? sm[tid - off] : 0;
        __syncthreads();
        sm[tid] += t;
        __syncthreads();
    }
    if (i < n) {
        int excl = sm[tid] - v + sbo;
        offs[i] = excl;
        cursor[i] = excl;
    }
}

// scatter edge ids into CSR slots (placement order arbitrary; sorted next)
__global__ void scatter_eid(const int* __restrict__ col, int* __restrict__ cursor,
                            int* __restrict__ eid, int E_) {
    int e = blockIdx.x * blockDim.x + threadIdx.x;
    if (e >= E_) return;
    int p = atomicAdd(&cursor[col[e]], 1);
    eid[p] = e;
}

// canonicalize: per-node insertion sort of edge ids (ascending), then
// deterministic deg = sum(ea) in sorted order, dis = rsqrt guard.
__global__ void sort_deg_kernel(int* __restrict__ eid, const int* __restrict__ offs,
                                const float* __restrict__ ea, float* __restrict__ dis, int n) {
    int i = blockIdx.x * blockDim.x + threadIdx.x;
    if (i >= n) return;
    int p0 = offs[i], p1 = offs[i + 1];
    for (int a = p0 + 1; a < p1; ++a) {
        int key = eid[a];
        int b = a - 1;
        while (b >= p0 && eid[b] > key) { eid[b + 1] = eid[b]; --b; }
        eid[b + 1] = key;
    }
    float dg = 0.f;
    for (int p = p0; p < p1; ++p) dg += ea[eid[p]];
    dis[i] = dg > 0.f ? rsqrtf(fmaxf(dg, EPSV)) : 0.f;
}

// pack (src_row, norm_weight) into int2 so agg does one 8B load per edge
__global__ void fill_csr(const int* __restrict__ eid, const int* __restrict__ row,
                         const int* __restrict__ col, const float* __restrict__ ea,
                         const float* __restrict__ dis, int2* __restrict__ csr, int E_) {
    int p = blockIdx.x * blockDim.x + threadIdx.x;
    if (p >= E_) return;
    int e = eid[p];
    int r = row[e], c = col[e];
    float w = dis[r] * ea[e] * dis[c];
    csr[p] = make_int2(r, __float_as_int(w));
}

// ---------------- batch norm (deterministic partials) ----------------
// 256 threads = 8 rows x 32 lanes (float4 each); LDS tree; block partials
// written TRANSPOSED (pS[d*NB + block]) so bn_reduce reads coalesced.

template <bool GATHER>
__global__ __launch_bounds__(256) void bn_stats(const float* __restrict__ src,
                                                const int* __restrict__ idx,
                                                float* __restrict__ pS,
                                                float* __restrict__ pQ, int n, int NB) {
    int sub = threadIdx.x >> 5;
    int q = threadIdx.x & 31;
    float4 s = make_float4(0, 0, 0, 0), s2 = make_float4(0, 0, 0, 0);
    for (int i = blockIdx.x * 8 + sub; i < n; i += gridDim.x * 8) {
        int r = GATHER ? idx[i] : i;
        float4 v = *(const float4*)&src[(long)r * D + q * 4];
        s.x += v.x; s.y += v.y; s.z += v.z; s.w += v.w;
        s2.x += v.x * v.x; s2.y += v.y * v.y; s2.z += v.z * v.z; s2.w += v.w * v.w;
    }
    __shared__ float4 redA[256], redB[256];
    redA[threadIdx.x] = s;
    redB[threadIdx.x] = s2;
    __syncthreads();
    for (int off = 128; off >= 32; off >>= 1) {
        if (threadIdx.x < off) {
            float4 a = redA[threadIdx.x + off], b = redB[threadIdx.x + off];
            redA[threadIdx.x].x += a.x; redA[threadIdx.x].y += a.y;
            redA[threadIdx.x].z += a.z; redA[threadIdx.x].w += a.w;
            redB[threadIdx.x].x += b.x; redB[threadIdx.x].y += b.y;
            redB[threadIdx.x].z += b.z; redB[threadIdx.x].w += b.w;
        }
        __syncthreads();
    }
    if (threadIdx.x < 32) {
        float4 a = redA[threadIdx.x], b = redB[threadIdx.x];
        int bofs = blockIdx.x;
        pS[(q * 4 + 0) * NB + bofs] = a.x;
        pS[(q * 4 + 1) * NB + bofs] = a.y;
        pS[(q * 4 + 2) * NB + bofs] = a.z;
        pS[(q * 4 + 3) * NB + bofs] = a.w;
        pQ[(q * 4 + 0) * NB + bofs] = b.x;
        pQ[(q * 4 + 1) * NB + bofs] = b.y;
        pQ[(q * 4 + 2) * NB + bofs] = b.z;
        pQ[(q * 4 + 3) * NB + bofs] = b.w;
    }
}

// one block per feature d; coalesced reads of pS[d*NB..], LDS tree reduce.
__global__ __launch_bounds__(256) void bn_reduce(const float* __restrict__ pS,
                                                 const float* __restrict__ pQ, int nb,
                                                 const float* __restrict__ gamma,
                                                 const float* __restrict__ beta,
                                                 float* __restrict__ scale,
                                                 float* __restrict__ shift, float n) {
    int d = blockIdx.x;
    int tid = threadIdx.x;
    float s = 0.f, q = 0.f;
    for (int b = tid; b < nb; b += 256) {
        s += pS[d * nb + b];
        q += pQ[d * nb + b];
    }
    __shared__ float smS[256], smQ[256];
    smS[tid] = s;
    smQ[tid] = q;
    __syncthreads();
    for (int off = 128; off > 0; off >>= 1) {
        if (tid < off) {
            smS[tid] += smS[tid + off];
            smQ[tid] += smQ[tid + off];
        }
        __syncthreads();
    }
    if (tid == 0) {
        float mean = smS[0] / n;
        float var = smQ[0] / n - mean * mean;
        float rstd = rsqrtf(var + EPSV);
        float sc = gamma[d] * rstd;
        scale[d] = sc;
        shift[d] = beta[d] - mean * sc;
    }
}

// ---------------- GEMM: h = (src*scale+shift) @ W ----------------
// 64 rows/block, 256 threads = 8 rowgroups x 32 colgroups, 8x4 micro-tile.
// x staged [r][k] stride 132 via float4 (b128 writes, BW-bound, no scalar
// conflicts); compute reads are 2-address broadcasts (free). W float4 from
// L2 with unroll-8 so 8 loads stay in flight.

template <bool GATHER>
__global__ __launch_bounds__(256) void gemm_bn(const float* __restrict__ src,
                                               const int* __restrict__ idx,
                                               const float* __restrict__ scale,
                                               const float* __restrict__ shift,
                                               const float* __restrict__ W,
                                               float* __restrict__ out, int n) {
    __shared__ float xs[64 * 132];  // 33.8 KB -> 4 blocks/CU
    int tid = threadIdx.x;
    int r0 = blockIdx.x * 64;
    const float4* scale4 = (const float4*)scale;
    const float4* shift4 = (const float4*)shift;
    for (int it = 0; it < 8; ++it) {
        int flat = it * 256 + tid;  // 0..2047
        int r = flat >> 5;          // 0..63
        int kq = flat & 31;         // float4 index along k
        int gr = r0 + r;
        float4 v = make_float4(0.f, 0.f, 0.f, 0.f);
        if (gr < n) {
            int srow = GATHER ? idx[gr] : gr;
            float4 x4 = *(const float4*)&src[(long)srow * D + kq * 4];
            float4 sc = scale4[kq], sh = shift4[kq];
            v = make_float4(x4.x * sc.x + sh.x, x4.y * sc.y + sh.y, x4.z * sc.z + sh.z,
                            x4.w * sc.w + sh.w);
        }
        *(float4*)&xs[r * 132 + kq * 4] = v;
    }
    __syncthreads();
    int cg = tid & 31;  // cols cg*4..cg*4+3
    int rg = tid >> 5;  // rows rg*8..rg*8+7
    float acc[8][4];
#pragma unroll
    for (int j = 0; j < 8; ++j)
#pragma unroll
        for (int q = 0; q < 4; ++q) acc[j][q] = 0.f;
    const float4* Wv = (const float4*)W;
#pragma unroll 8
    for (int k = 0; k < 128; ++k) {
        float4 wv = Wv[k * 32 + cg];
        float xr[8];
#pragma unroll
        for (int j = 0; j < 8; ++j) xr[j] = xs[(rg * 8 + j) * 132 + k];
#pragma unroll
        for (int j = 0; j < 8; ++j) {
            acc[j][0] += xr[j] * wv.x;
            acc[j][1] += xr[j] * wv.y;
            acc[j][2] += xr[j] * wv.z;
            acc[j][3] += xr[j] * wv.w;
        }
    }
#pragma unroll
    for (int j = 0; j < 8; ++j) {
        int gr = r0 + rg * 8 + j;
        if (gr < n) {
            *(float4*)&out[(long)gr * D + cg * 4] =
                make_float4(acc[j][0], acc[j][1], acc[j][2], acc[j][3]);
        }
    }
}

// ---------------- aggregation: x[i] = relu(b + sum_e w_e * h[row_e]) ----------------
// 1 node per wave (64 lanes x float2); 4 nodes per block; 8-edge unroll for MLP.

__global__ __launch_bounds__(256) void agg_kernel(const float2* __restrict__ h2,
                                                  const int2* __restrict__ csr,
                                                  const int* __restrict__ offs,
                                                  const float2* __restrict__ bias2,
                                                  float2* __restrict__ xout, int n) {
    int node = blockIdx.x * 4 + (threadIdx.x >> 6);
    int d = threadIdx.x & 63;
    if (node >= n) return;
    int p0 = offs[node], p1 = offs[node + 1];
    float2 acc = bias2[d];
    int p = p0;
    for (; p + 8 <= p1; p += 8) {
        int2 e0 = csr[p], e1 = csr[p + 1], e2 = csr[p + 2], e3 = csr[p + 3];
        int2 e4 = csr[p + 4], e5 = csr[p + 5], e6 = csr[p + 6], e7 = csr[p + 7];
        float2 v0 = h2[(long)e0.x * 64 + d];
        float2 v1 = h2[(long)e1.x * 64 + d];
        float2 v2 = h2[(long)e2.x * 64 + d];
        float2 v3 = h2[(long)e3.x * 64 + d];
        float2 v4 = h2[(long)e4.x * 64 + d];
        float2 v5 = h2[(long)e5.x * 64 + d];
        float2 v6 = h2[(long)e6.x * 64 + d];
        float2 v7 = h2[(long)e7.x * 64 + d];
        float w0 = __int_as_float(e0.y), w1 = __int_as_float(e1.y);
        float w2 = __int_as_float(e2.y), w3 = __int_as_float(e3.y);
        float w4 = __int_as_float(e4.y), w5 = __int_as_float(e5.y);
        float w6 = __int_as_float(e6.y), w7 = __int_as_float(e7.y);
        acc.x += w0 * v0.x; acc.y += w0 * v0.y;
        acc.x += w1 * v1.x; acc.y += w1 * v1.y;
        acc.x += w2 * v2.x; acc.y += w2 * v2.y;
        acc.x += w3 * v3.x; acc.y += w3 * v3.y;
        acc.x += w4 * v4.x; acc.y += w4 * v4.y;
        acc.x += w5 * v5.x; acc.y += w5 * v5.y;
        acc.x += w6 * v6.x; acc.y += w6 * v6.y;
        acc.x += w7 * v7.x; acc.y += w7 * v7.y;
    }
    for (; p < p1; ++p) {
        int2 e = csr[p];
        float2 v = h2[(long)e.x * 64 + d];
        float w = __int_as_float(e.y);
        acc.x += w * v.x; acc.y += w * v.y;
    }
    xout[(long)node * 64 + d] = make_float2(fmaxf(acc.x, 0.f), fmaxf(acc.y, 0.f));
}

// ---------------- softmax pooling (segment bounds found in-block) ----------------

__global__ __launch_bounds__(512) void pool_kernel(const float* __restrict__ tfidf,
                                                   const int* __restrict__ batch,
                                                   const float* __restrict__ x,
                                                   float* __restrict__ out, int n) {
    int g = blockIdx.x;
    int tid = threadIdx.x;
    __shared__ int sbounds[2];
    if (tid < 2) {
        int target = g + tid;
        int lo = 0, hi = n;
        while (lo < hi) {
            int mid = (lo + hi) >> 1;
            if (batch[mid] < target) lo = mid + 1;
            else hi = mid;
        }
        sbounds[tid] = lo;
    }
    __syncthreads();
    int s0 = sbounds[0], s1 = sbounds[1];
    int d = tid & 127, sub = tid >> 7;  // 4-way node split
    __shared__ float red[512];
    // pass 1: segment max of tfidf
    float m = -1e30f;
    for (int i = s0 + tid; i < s1; i += 512) m = fmaxf(m, tfidf[i]);
    red[tid] = m;
    __syncthreads();
    for (int off = 256; off > 0; off >>= 1) {
        if (tid < off) red[tid] = fmaxf(red[tid], red[tid + off]);
        __syncthreads();
    }
    m = red[0];
    __syncthreads();
    // pass 2: sum of exp
    float s = 0.f;
    for (int i = s0 + tid; i < s1; i += 512) s += __expf(tfidf[i] - m);
    red[tid] = s;
    __syncthreads();
    for (int off = 256; off > 0; off >>= 1) {
        if (tid < off) red[tid] += red[tid + off];
        __syncthreads();
    }
    s = red[0];
    __syncthreads();
    // pass 3: weighted feature sum, 4 nodes in flight
    float acc = 0.f;
    for (int i = s0 + sub; i < s1; i += 4) acc += __expf(tfidf[i] - m) * x[(long)i * D + d];
    red[tid] = acc;
    __syncthreads();
    if (tid < 128) {
        float a = red[d] + red[128 + d] + red[256 + d] + red[384 + d];
        out[g * D + d] = (s1 > s0) ? a / s : 0.f;
    }
}

// ---------------- launch ----------------

extern "C" void kernel_launch(void* const* d_in, const int* in_sizes, int n_in, void* d_out,
                              int out_size, void* d_ws, size_t ws_size, hipStream_t stream) {
    const int N = in_sizes[0];
    const int E = in_sizes[4];
    const int G = out_size / D;
    const int BN_GRID = 512;

    const int* x_index = (const int*)d_in[0];
    const float* tfidf = (const float*)d_in[1];
    const int* ei_row = (const int*)d_in[2];
    const int* ei_col = ei_row + E;
    const int* batch = (const int*)d_in[3];
    const float* edge_attr = (const float*)d_in[4];
    const float* emb = (const float*)d_in[5];
    const float* gamma1 = (const float*)d_in[6];
    const float* beta1 = (const float*)d_in[7];
    const float* W1 = (const float*)d_in[8];
    const float* b1 = (const float*)d_in[9];
    const float* gamma2 = (const float*)d_in[10];
    const float* beta2 = (const float*)d_in[11];
    const float* W2 = (const float*)d_in[12];
    const float* b2 = (const float*)d_in[13];
    float* out = (float*)d_out;

    // ---- workspace carve (256B aligned) ----
    size_t off = 0;
    char* base = (char*)d_ws;
    auto carve = [&](size_t bytes) -> void* {
        void* p = base + off;
        off = (off + bytes + 255) & ~(size_t)255;
        return p;
    };
    float* bufA = (float*)carve((size_t)N * D * 4);  // h (gemm output)
    float* bufB = (float*)carve((size_t)N * D * 4);  // x (layer output)
    int* eid = (int*)carve((size_t)E * 4);           // CSR edge ids
    int2* csr = (int2*)carve((size_t)E * 8);         // packed (row, w)
    int* cnt = (int*)carve((size_t)N * 4);           // zeroed each launch
    float* dis = (float*)carve((size_t)N * 4);
    int* offs = (int*)carve((size_t)(N + 1) * 4);
    int* cursor = (int*)carve((size_t)N * 4);
    int* bsum = (int*)carve(64 * 4);
    float* scale1 = (float*)carve(D * 4);
    float* shift1 = (float*)carve(D * 4);
    float* scale2 = (float*)carve(D * 4);
    float* shift2 = (float*)carve(D * 4);
    float* pS = (float*)carve((size_t)BN_GRID * D * 4);
    float* pQ = (float*)carve((size_t)BN_GRID * D * 4);
    (void)ws_size;
    (void)n_in;

    hipMemsetAsync(cnt, 0, (size_t)N * 4, stream);

    // ---- edge preprocessing: CSR (deterministic; shared by both layers) ----
    hist_kernel<<<cdiv(E, 256), 256, 0, stream>>>(ei_col, cnt, E);
    int nb = cdiv(N, 1024);
    scan_chunk_sums<<<nb, 1024, 0, stream>>>(cnt, bsum, N);
    scan_final<<<nb, 1024, 0, stream>>>(cnt, bsum, nb, offs, cursor, N, E);
    scatter_eid<<<cdiv(E, 256), 256, 0, stream>>>(ei_col, cursor, eid, E);
    sort_deg_kernel<<<cdiv(N, 256), 256, 0, stream>>>(eid, offs, edge_attr, dis, N);
    fill_csr<<<cdiv(E, 256), 256, 0, stream>>>(eid, ei_row, ei_col, edge_attr, dis, csr, E);

    // ---- layer 1 ----
    bn_stats<true><<<BN_GRID, 256, 0, stream>>>(emb, x_index, pS, pQ, N, BN_GRID);
    bn_reduce<<<D, 256, 0, stream>>>(pS, pQ, BN_GRID, gamma1, beta1, scale1, shift1, (float)N);
    gemm_bn<true><<<cdiv(N, 64), 256, 0, stream>>>(emb, x_index, scale1, shift1, W1, bufA, N);
    agg_kernel<<<cdiv(N, 4), 256, 0, stream>>>((const float2*)bufA, csr, offs,
                                               (const float2*)b1, (float2*)bufB, N);

    // ---- layer 2 ----
    bn_stats<false><<<BN_GRID, 256, 0, stream>>>(bufB, nullptr, pS, pQ, N, BN_GRID);
    bn_reduce<<<D, 256, 0, stream>>>(pS, pQ, BN_GRID, gamma2, beta2, scale2, shift2, (float)N);
    gemm_bn<false><<<cdiv(N, 64), 256, 0, stream>>>(bufB, nullptr, scale2, shift2, W2, bufA, N);
    agg_kernel<<<cdiv(N, 4), 256, 0, stream>>>((const float2*)bufA, csr, offs,
                                               (const float2*)b2, (float2*)bufB, N);

    // ---- softmax pooling (bounds fused into pool) ----
    pool_kernel<<<G, 512, 0, stream>>>(tfidf, batch, bufB, out, N);
}

// Round 6
// 399.705 us; speedup vs baseline: 1.6571x; 1.0081x over previous
//
#include <hip/hip_runtime.h>
#include <hip/hip_bf16.h>

#define D 128
#define EPSV 1e-5f

static inline int cdiv(int a, int b) { return (a + b - 1) / b; }

// bf16 bit helpers (RNE pack, cheap unpack)
__device__ __forceinline__ unsigned short f2bf(float f) {
    unsigned int x = __float_as_uint(f);
    unsigned int r = x + 0x7fffu + ((x >> 16) & 1u);
    return (unsigned short)(r >> 16);
}

// ---------------- edge preprocessing (fully deterministic) ----------------

__global__ void hist_kernel(const int* __restrict__ col, int* __restrict__ cnt, int E_) {
    int e = blockIdx.x * blockDim.x + threadIdx.x;
    if (e >= E_) return;
    atomicAdd(&cnt[col[e]], 1);  // int atomics: result order-independent
}

// scan over cnt[N] (chunk = 1024): block sums, then final scan (tops fused)
__global__ void scan_chunk_sums(const int* __restrict__ cnt, int* __restrict__ bsum, int n) {
    __shared__ int sm[1024];
    int i = blockIdx.x * 1024 + threadIdx.x;
    sm[threadIdx.x] = (i < n) ? cnt[i] : 0;
    __syncthreads();
    for (int off = 512; off > 0; off >>= 1) {
        if (threadIdx.x < off) sm[threadIdx.x] += sm[threadIdx.x + off];
        __syncthreads();
    }
    if (threadIdx.x == 0) bsum[blockIdx.x] = sm[0];
}

// final scan; block offset computed in-block from bsum (scan_tops fused)
__global__ void scan_final(const int* __restrict__ cnt, const int* __restrict__ bsum, int nbk,
                           int* __restrict__ offs, int* __restrict__ cursor, int n, int E_) {
    __shared__ int sm[1024];
    __shared__ int sbo;
    int tid = threadIdx.x;
    int bv = (tid < nbk && tid < blockIdx.x) ? bsum[tid] : 0;
    sm[tid] = bv;
    __syncthreads();
    for (int off = 512; off > 0; off >>= 1) {
        if (tid < off) sm[tid] += sm[tid + off];
        __syncthreads();
    }
    if (tid == 0) {
        sbo = sm[0];
        if (blockIdx.x == 0) offs[n] = E_;
    }
    __syncthreads();
    int i = blockIdx.x * 1024 + tid;
    int v = (i < n) ? cnt[i] : 0;
    sm[tid] = v;
    __syncthreads();
    for (int off = 1; off < 1024; off <<= 1) {
        int t = (tid >= off) ? sm[tid - off] : 0;
        __syncthreads();
        sm[tid] += t;
        __syncthreads();
    }
    if (i < n) {
        int excl = sm[tid] - v + sbo;
        offs[i] = excl;
        cursor[i] = excl;
    }
}

// scatter edge ids into CSR slots (placement order arbitrary; sorted next)
__global__ void scatter_eid(const int* __restrict__ col, int* __restrict__ cursor,
                            int* __restrict__ eid, int E_) {
    int e = blockIdx.x * blockDim.x + threadIdx.x;
    if (e >= E_) return;
    int p = atomicAdd(&cursor[col[e]], 1);
    eid[p] = e;
}

// canonicalize: per-node insertion sort of edge ids (ascending) in a local
// (scratch) array — lane-swizzled, far cheaper than in-place global; then
// deterministic deg = sum(ea) in sorted order, dis = rsqrt guard.
__global__ void sort_deg_kernel(int* __restrict__ eid, const int* __restrict__ offs,
                                const float* __restrict__ ea, float* __restrict__ dis, int n) {
    int i = blockIdx.x * blockDim.x + threadIdx.x;
    if (i >= n) return;
    int p0 = offs[i], p1 = offs[i + 1];
    int deg = p1 - p0;
    float dg = 0.f;
    if (deg <= 64) {
        int loc[64];
        for (int j = 0; j < deg; ++j) loc[j] = eid[p0 + j];
        for (int a = 1; a < deg; ++a) {
            int key = loc[a];
            int b = a - 1;
            while (b >= 0 && loc[b] > key) { loc[b + 1] = loc[b]; --b; }
            loc[b + 1] = key;
        }
        for (int j = 0; j < deg; ++j) {
            eid[p0 + j] = loc[j];
            dg += ea[loc[j]];
        }
    } else {  // fallback (never hit for Poisson(12) degrees, kept for safety)
        for (int a = p0 + 1; a < p1; ++a) {
            int key = eid[a];
            int b = a - 1;
            while (b >= p0 && eid[b] > key) { eid[b + 1] = eid[b]; --b; }
            eid[b + 1] = key;
        }
        for (int p = p0; p < p1; ++p) dg += ea[eid[p]];
    }
    dis[i] = dg > 0.f ? rsqrtf(fmaxf(dg, EPSV)) : 0.f;
}

// pack (src_row, norm_weight) into int2 so agg does one 8B load per edge
__global__ void fill_csr(const int* __restrict__ eid, const int* __restrict__ row,
                         const int* __restrict__ col, const float* __restrict__ ea,
                         const float* __restrict__ dis, int2* __restrict__ csr, int E_) {
    int p = blockIdx.x * blockDim.x + threadIdx.x;
    if (p >= E_) return;
    int e = eid[p];
    int r = row[e], c = col[e];
    float w = dis[r] * ea[e] * dis[c];
    csr[p] = make_int2(r, __float_as_int(w));
}

// ---------------- batch norm (deterministic partials) ----------------
// 256 threads = 8 rows x 32 lanes (float4 each); LDS tree; block partials
// written TRANSPOSED (pS[d*NB + block]) so bn_reduce reads coalesced.

template <bool GATHER>
__global__ __launch_bounds__(256) void bn_stats(const float* __restrict__ src,
                                                const int* __restrict__ idx,
                                                float* __restrict__ pS,
                                                float* __restrict__ pQ, int n, int NB) {
    int sub = threadIdx.x >> 5;
    int q = threadIdx.x & 31;
    float4 s = make_float4(0, 0, 0, 0), s2 = make_float4(0, 0, 0, 0);
    for (int i = blockIdx.x * 8 + sub; i < n; i += gridDim.x * 8) {
        int r = GATHER ? idx[i] : i;
        float4 v = *(const float4*)&src[(long)r * D + q * 4];
        s.x += v.x; s.y += v.y; s.z += v.z; s.w += v.w;
        s2.x += v.x * v.x; s2.y += v.y * v.y; s2.z += v.z * v.z; s2.w += v.w * v.w;
    }
    __shared__ float4 redA[256], redB[256];
    redA[threadIdx.x] = s;
    redB[threadIdx.x] = s2;
    __syncthreads();
    for (int off = 128; off >= 32; off >>= 1) {
        if (threadIdx.x < off) {
            float4 a = redA[threadIdx.x + off], b = redB[threadIdx.x + off];
            redA[threadIdx.x].x += a.x; redA[threadIdx.x].y += a.y;
            redA[threadIdx.x].z += a.z; redA[threadIdx.x].w += a.w;
            redB[threadIdx.x].x += b.x; redB[threadIdx.x].y += b.y;
            redB[threadIdx.x].z += b.z; redB[threadIdx.x].w += b.w;
        }
        __syncthreads();
    }
    if (threadIdx.x < 32) {
        float4 a = redA[threadIdx.x], b = redB[threadIdx.x];
        int bofs = blockIdx.x;
        pS[(q * 4 + 0) * NB + bofs] = a.x;
        pS[(q * 4 + 1) * NB + bofs] = a.y;
        pS[(q * 4 + 2) * NB + bofs] = a.z;
        pS[(q * 4 + 3) * NB + bofs] = a.w;
        pQ[(q * 4 + 0) * NB + bofs] = b.x;
        pQ[(q * 4 + 1) * NB + bofs] = b.y;
        pQ[(q * 4 + 2) * NB + bofs] = b.z;
        pQ[(q * 4 + 3) * NB + bofs] = b.w;
    }
}

// one block per feature d; coalesced reads of pS[d*NB..], LDS tree reduce.
__global__ __launch_bounds__(256) void bn_reduce(const float* __restrict__ pS,
                                                 const float* __restrict__ pQ, int nb,
                                                 const float* __restrict__ gamma,
                                                 const float* __restrict__ beta,
                                                 float* __restrict__ scale,
                                                 float* __restrict__ shift, float n) {
    int d = blockIdx.x;
    int tid = threadIdx.x;
    float s = 0.f, q = 0.f;
    for (int b = tid; b < nb; b += 256) {
        s += pS[d * nb + b];
        q += pQ[d * nb + b];
    }
    __shared__ float smS[256], smQ[256];
    smS[tid] = s;
    smQ[tid] = q;
    __syncthreads();
    for (int off = 128; off > 0; off >>= 1) {
        if (tid < off) {
            smS[tid] += smS[tid + off];
            smQ[tid] += smQ[tid + off];
        }
        __syncthreads();
    }
    if (tid == 0) {
        float mean = smS[0] / n;
        float var = smQ[0] / n - mean * mean;
        float rstd = rsqrtf(var + EPSV);
        float sc = gamma[d] * rstd;
        scale[d] = sc;
        shift[d] = beta[d] - mean * sc;
    }
}

// ---------------- GEMM: h = (src*scale+shift) @ W, output bf16 ----------------
// 64 rows/block, 256 threads = 8 rowgroups x 32 colgroups, 8x4 micro-tile.

template <bool GATHER>
__global__ __launch_bounds__(256) void gemm_bn(const float* __restrict__ src,
                                               const int* __restrict__ idx,
                                               const float* __restrict__ scale,
                                               const float* __restrict__ shift,
                                               const float* __restrict__ W,
                                               unsigned short* __restrict__ outb, int n) {
    __shared__ float xs[64 * 132];  // 33.8 KB
    int tid = threadIdx.x;
    int r0 = blockIdx.x * 64;
    const float4* scale4 = (const float4*)scale;
    const float4* shift4 = (const float4*)shift;
    for (int it = 0; it < 8; ++it) {
        int flat = it * 256 + tid;  // 0..2047
        int r = flat >> 5;          // 0..63
        int kq = flat & 31;         // float4 index along k
        int gr = r0 + r;
        float4 v = make_float4(0.f, 0.f, 0.f, 0.f);
        if (gr < n) {
            int srow = GATHER ? idx[gr] : gr;
            float4 x4 = *(const float4*)&src[(long)srow * D + kq * 4];
            float4 sc = scale4[kq], sh = shift4[kq];
            v = make_float4(x4.x * sc.x + sh.x, x4.y * sc.y + sh.y, x4.z * sc.z + sh.z,
                            x4.w * sc.w + sh.w);
        }
        *(float4*)&xs[r * 132 + kq * 4] = v;
    }
    __syncthreads();
    int cg = tid & 31;  // cols cg*4..cg*4+3
    int rg = tid >> 5;  // rows rg*8..rg*8+7
    float acc[8][4];
#pragma unroll
    for (int j = 0; j < 8; ++j)
#pragma unroll
        for (int q = 0; q < 4; ++q) acc[j][q] = 0.f;
    const float4* Wv = (const float4*)W;
#pragma unroll 8
    for (int k = 0; k < 128; ++k) {
        float4 wv = Wv[k * 32 + cg];
        float xr[8];
#pragma unroll
        for (int j = 0; j < 8; ++j) xr[j] = xs[(rg * 8 + j) * 132 + k];
#pragma unroll
        for (int j = 0; j < 8; ++j) {
            acc[j][0] += xr[j] * wv.x;
            acc[j][1] += xr[j] * wv.y;
            acc[j][2] += xr[j] * wv.z;
            acc[j][3] += xr[j] * wv.w;
        }
    }
#pragma unroll
    for (int j = 0; j < 8; ++j) {
        int gr = r0 + rg * 8 + j;
        if (gr < n) {
            ushort4 o = make_ushort4(f2bf(acc[j][0]), f2bf(acc[j][1]), f2bf(acc[j][2]),
                                     f2bf(acc[j][3]));
            *(ushort4*)&outb[(long)gr * D + cg * 4] = o;
        }
    }
}

// ---------------- aggregation: x[i] = relu(b + sum_e w_e * h[row_e]) ----------------
// h is bf16 (256B rows): 1 node per wave, lane d holds features 2d,2d+1
// (one dword gather per edge per lane); fp32 accumulate; 8-edge unroll.

__global__ __launch_bounds__(256) void agg_kernel(const unsigned int* __restrict__ hw,
                                                  const int2* __restrict__ csr,
                                                  const int* __restrict__ offs,
                                                  const float2* __restrict__ bias2,
                                                  float2* __restrict__ xout, int n) {
    int node = blockIdx.x * 4 + (threadIdx.x >> 6);
    int d = threadIdx.x & 63;
    if (node >= n) return;
    int p0 = offs[node], p1 = offs[node + 1];
    float2 acc = bias2[d];
    int p = p0;
    for (; p + 8 <= p1; p += 8) {
        int2 e0 = csr[p], e1 = csr[p + 1], e2 = csr[p + 2], e3 = csr[p + 3];
        int2 e4 = csr[p + 4], e5 = csr[p + 5], e6 = csr[p + 6], e7 = csr[p + 7];
        unsigned int u0 = hw[(long)e0.x * 64 + d];
        unsigned int u1 = hw[(long)e1.x * 64 + d];
        unsigned int u2 = hw[(long)e2.x * 64 + d];
        unsigned int u3 = hw[(long)e3.x * 64 + d];
        unsigned int u4 = hw[(long)e4.x * 64 + d];
        unsigned int u5 = hw[(long)e5.x * 64 + d];
        unsigned int u6 = hw[(long)e6.x * 64 + d];
        unsigned int u7 = hw[(long)e7.x * 64 + d];
        float w0 = __int_as_float(e0.y), w1 = __int_as_float(e1.y);
        float w2 = __int_as_float(e2.y), w3 = __int_as_float(e3.y);
        float w4 = __int_as_float(e4.y), w5 = __int_as_float(e5.y);
        float w6 = __int_as_float(e6.y), w7 = __int_as_float(e7.y);
        acc.x += w0 * __uint_as_float(u0 << 16); acc.y += w0 * __uint_as_float(u0 & 0xffff0000u);
        acc.x += w1 * __uint_as_float(u1 << 16); acc.y += w1 * __uint_as_float(u1 & 0xffff0000u);
        acc.x += w2 * __uint_as_float(u2 << 16); acc.y += w2 * __uint_as_float(u2 & 0xffff0000u);
        acc.x += w3 * __uint_as_float(u3 << 16); acc.y += w3 * __uint_as_float(u3 & 0xffff0000u);
        acc.x += w4 * __uint_as_float(u4 << 16); acc.y += w4 * __uint_as_float(u4 & 0xffff0000u);
        acc.x += w5 * __uint_as_float(u5 << 16); acc.y += w5 * __uint_as_float(u5 & 0xffff0000u);
        acc.x += w6 * __uint_as_float(u6 << 16); acc.y += w6 * __uint_as_float(u6 & 0xffff0000u);
        acc.x += w7 * __uint_as_float(u7 << 16); acc.y += w7 * __uint_as_float(u7 & 0xffff0000u);
    }
    for (; p < p1; ++p) {
        int2 e = csr[p];
        unsigned int u = hw[(long)e.x * 64 + d];
        float w = __int_as_float(e.y);
        acc.x += w * __uint_as_float(u << 16);
        acc.y += w * __uint_as_float(u & 0xffff0000u);
    }
    xout[(long)node * 64 + d] = make_float2(fmaxf(acc.x, 0.f), fmaxf(acc.y, 0.f));
}

// ---------------- softmax pooling (segment bounds found in-block) ----------------

__global__ __launch_bounds__(512) void pool_kernel(const float* __restrict__ tfidf,
                                                   const int* __restrict__ batch,
                                                   const float* __restrict__ x,
                                                   float* __restrict__ out, int n) {
    int g = blockIdx.x;
    int tid = threadIdx.x;
    __shared__ int sbounds[2];
    if (tid < 2) {
        int target = g + tid;
        int lo = 0, hi = n;
        while (lo < hi) {
            int mid = (lo + hi) >> 1;
            if (batch[mid] < target) lo = mid + 1;
            else hi = mid;
        }
        sbounds[tid] = lo;
    }
    __syncthreads();
    int s0 = sbounds[0], s1 = sbounds[1];
    int d = tid & 127, sub = tid >> 7;  // 4-way node split
    __shared__ float red[512];
    float m = -1e30f;
    for (int i = s0 + tid; i < s1; i += 512) m = fmaxf(m, tfidf[i]);
    red[tid] = m;
    __syncthreads();
    for (int off = 256; off > 0; off >>= 1) {
        if (tid < off) red[tid] = fmaxf(red[tid], red[tid + off]);
        __syncthreads();
    }
    m = red[0];
    __syncthreads();
    float s = 0.f;
    for (int i = s0 + tid; i < s1; i += 512) s += __expf(tfidf[i] - m);
    red[tid] = s;
    __syncthreads();
    for (int off = 256; off > 0; off >>= 1) {
        if (tid < off) red[tid] += red[tid + off];
        __syncthreads();
    }
    s = red[0];
    __syncthreads();
    float acc = 0.f;
    for (int i = s0 + sub; i < s1; i += 4) acc += __expf(tfidf[i] - m) * x[(long)i * D + d];
    red[tid] = acc;
    __syncthreads();
    if (tid < 128) {
        float a = red[d] + red[128 + d] + red[256 + d] + red[384 + d];
        out[g * D + d] = (s1 > s0) ? a / s : 0.f;
    }
}

// ---------------- launch ----------------

extern "C" void kernel_launch(void* const* d_in, const int* in_sizes, int n_in, void* d_out,
                              int out_size, void* d_ws, size_t ws_size, hipStream_t stream) {
    const int N = in_sizes[0];
    const int E = in_sizes[4];
    const int G = out_size / D;
    const int BN_GRID = 512;

    const int* x_index = (const int*)d_in[0];
    const float* tfidf = (const float*)d_in[1];
    const int* ei_row = (const int*)d_in[2];
    const int* ei_col = ei_row + E;
    const int* batch = (const int*)d_in[3];
    const float* edge_attr = (const float*)d_in[4];
    const float* emb = (const float*)d_in[5];
    const float* gamma1 = (const float*)d_in[6];
    const float* beta1 = (const float*)d_in[7];
    const float* W1 = (const float*)d_in[8];
    const float* b1 = (const float*)d_in[9];
    const float* gamma2 = (const float*)d_in[10];
    const float* beta2 = (const float*)d_in[11];
    const float* W2 = (const float*)d_in[12];
    const float* b2 = (const float*)d_in[13];
    float* out = (float*)d_out;

    // ---- workspace carve (256B aligned) ----
    size_t off = 0;
    char* base = (char*)d_ws;
    auto carve = [&](size_t bytes) -> void* {
        void* p = base + off;
        off = (off + bytes + 255) & ~(size_t)255;
        return p;
    };
    unsigned short* bufA = (unsigned short*)carve((size_t)N * D * 2);  // h (bf16)
    float* bufB = (float*)carve((size_t)N * D * 4);                    // x (layer output)
    int* eid = (int*)carve((size_t)E * 4);                             // CSR edge ids
    int2* csr = (int2*)carve((size_t)E * 8);                           // packed (row, w)
    int* cnt = (int*)carve((size_t)N * 4);                             // zeroed each launch
    float* dis = (float*)carve((size_t)N * 4);
    int* offs = (int*)carve((size_t)(N + 1) * 4);
    int* cursor = (int*)carve((size_t)N * 4);
    int* bsum = (int*)carve(64 * 4);
    float* scale1 = (float*)carve(D * 4);
    float* shift1 = (float*)carve(D * 4);
    float* scale2 = (float*)carve(D * 4);
    float* shift2 = (float*)carve(D * 4);
    float* pS = (float*)carve((size_t)BN_GRID * D * 4);
    float* pQ = (float*)carve((size_t)BN_GRID * D * 4);
    (void)ws_size;
    (void)n_in;

    hipMemsetAsync(cnt, 0, (size_t)N * 4, stream);

    // ---- edge preprocessing: CSR (deterministic; shared by both layers) ----
    hist_kernel<<<cdiv(E, 256), 256, 0, stream>>>(ei_col, cnt, E);
    int nb = cdiv(N, 1024);
    scan_chunk_sums<<<nb, 1024, 0, stream>>>(cnt, bsum, N);
    scan_final<<<nb, 1024, 0, stream>>>(cnt, bsum, nb, offs, cursor, N, E);
    scatter_eid<<<cdiv(E, 256), 256, 0, stream>>>(ei_col, cursor, eid, E);
    sort_deg_kernel<<<cdiv(N, 256), 256, 0, stream>>>(eid, offs, edge_attr, dis, N);
    fill_csr<<<cdiv(E, 256), 256, 0, stream>>>(eid, ei_row, ei_col, edge_attr, dis, csr, E);

    // ---- layer 1 ----
    bn_stats<true><<<BN_GRID, 256, 0, stream>>>(emb, x_index, pS, pQ, N, BN_GRID);
    bn_reduce<<<D, 256, 0, stream>>>(pS, pQ, BN_GRID, gamma1, beta1, scale1, shift1, (float)N);
    gemm_bn<true><<<cdiv(N, 64), 256, 0, stream>>>(emb, x_index, scale1, shift1, W1, bufA, N);
    agg_kernel<<<cdiv(N, 4), 256, 0, stream>>>((const unsigned int*)bufA, csr, offs,
                                               (const float2*)b1, (float2*)bufB, N);

    // ---- layer 2 ----
    bn_stats<false><<<BN_GRID, 256, 0, stream>>>(bufB, nullptr, pS, pQ, N, BN_GRID);
    bn_reduce<<<D, 256, 0, stream>>>(pS, pQ, BN_GRID, gamma2, beta2, scale2, shift2, (float)N);
    gemm_bn<false><<<cdiv(N, 64), 256, 0, stream>>>(bufB, nullptr, scale2, shift2, W2, bufA, N);
    agg_kernel<<<cdiv(N, 4), 256, 0, stream>>>((const unsigned int*)bufA, csr, offs,
                                               (const float2*)b2, (float2*)bufB, N);

    // ---- softmax pooling (bounds fused into pool) ----
    pool_kernel<<<G, 512, 0, stream>>>(tfidf, batch, bufB, out, N);
}

// Round 7
// 369.006 us; speedup vs baseline: 1.7950x; 1.0832x over previous
//
#include <hip/hip_runtime.h>
#include <hip/hip_bf16.h>

#define D 128
#define EPSV 1e-5f

static inline int cdiv(int a, int b) { return (a + b - 1) / b; }

// bf16 bit helpers (RNE pack, cheap unpack)
__device__ __forceinline__ unsigned short f2bf(float f) {
    unsigned int x = __float_as_uint(f);
    unsigned int r = x + 0x7fffu + ((x >> 16) & 1u);
    return (unsigned short)(r >> 16);
}

// ---------------- edge preprocessing (fully deterministic) ----------------

__global__ void hist_kernel(const int* __restrict__ col, int* __restrict__ cnt, int E_) {
    int e = blockIdx.x * blockDim.x + threadIdx.x;
    if (e >= E_) return;
    atomicAdd(&cnt[col[e]], 1);  // int atomics: result order-independent
}

// scan over cnt[N] (chunk = 1024): block sums, then final scan (tops fused)
__global__ void scan_chunk_sums(const int* __restrict__ cnt, int* __restrict__ bsum, int n) {
    __shared__ int sm[1024];
    int i = blockIdx.x * 1024 + threadIdx.x;
    sm[threadIdx.x] = (i < n) ? cnt[i] : 0;
    __syncthreads();
    for (int off = 512; off > 0; off >>= 1) {
        if (threadIdx.x < off) sm[threadIdx.x] += sm[threadIdx.x + off];
        __syncthreads();
    }
    if (threadIdx.x == 0) bsum[blockIdx.x] = sm[0];
}

// final scan; block offset computed in-block from bsum (scan_tops fused)
__global__ void scan_final(const int* __restrict__ cnt, const int* __restrict__ bsum, int nbk,
                           int* __restrict__ offs, int* __restrict__ cursor, int n, int E_) {
    __shared__ int sm[1024];
    __shared__ int sbo;
    int tid = threadIdx.x;
    int bv = (tid < nbk && tid < blockIdx.x) ? bsum[tid] : 0;
    sm[tid] = bv;
    __syncthreads();
    for (int off = 512; off > 0; off >>= 1) {
        if (tid < off) sm[tid] += sm[tid + off];
        __syncthreads();
    }
    if (tid == 0) {
        sbo = sm[0];
        if (blockIdx.x == 0) offs[n] = E_;
    }
    __syncthreads();
    int i = blockIdx.x * 1024 + tid;
    int v = (i < n) ? cnt[i] : 0;
    sm[tid] = v;
    __syncthreads();
    for (int off = 1; off < 1024; off <<= 1) {
        int t = (tid >= off) ? sm[tid - off] : 0;
        __syncthreads();
        sm[tid] += t;
        __syncthreads();
    }
    if (i < n) {
        int excl = sm[tid] - v + sbo;
        offs[i] = excl;
        cursor[i] = excl;
    }
}

// scatter edge ids into CSR slots (placement order arbitrary; sorted next)
__global__ void scatter_eid(const int* __restrict__ col, int* __restrict__ cursor,
                            int* __restrict__ eid, int E_) {
    int e = blockIdx.x * blockDim.x + threadIdx.x;
    if (e >= E_) return;
    int p = atomicAdd(&cursor[col[e]], 1);
    eid[p] = e;
}

// canonicalize each node's edge-id list with a wave-level bitonic sorting
// network (64 lanes, sentinel INT_MAX past degree) — all-register, fully
// deterministic; then deterministic tree-sum of ea for deg -> dis.
__global__ __launch_bounds__(256) void sort_deg_kernel(int* __restrict__ eid,
                                                       const int* __restrict__ offs,
                                                       const float* __restrict__ ea,
                                                       float* __restrict__ dis, int n) {
    int node = blockIdx.x * 4 + (threadIdx.x >> 6);
    int lane = threadIdx.x & 63;
    if (node >= n) return;
    int p0 = offs[node], p1 = offs[node + 1];
    int deg = p1 - p0;
    if (deg <= 64) {
        int id = (lane < deg) ? eid[p0 + lane] : 0x7fffffff;
        for (int k = 2; k <= 64; k <<= 1) {
            for (int j = k >> 1; j > 0; j >>= 1) {
                int partner = __shfl_xor(id, j, 64);
                bool up = ((lane & k) == 0);
                bool keepMin = ((lane & j) == 0);
                int mn = id < partner ? id : partner;
                int mx = id < partner ? partner : id;
                id = (up == keepMin) ? mn : mx;
            }
        }
        if (lane < deg) eid[p0 + lane] = id;
        float v = (lane < deg) ? ea[id] : 0.f;
        for (int off = 32; off > 0; off >>= 1) v += __shfl_xor(v, off, 64);
        if (lane == 0) dis[node] = v > 0.f ? rsqrtf(fmaxf(v, EPSV)) : 0.f;
    } else {
        // serial fallback (unreachable for this degree distribution)
        if (lane == 0) {
            for (int a = p0 + 1; a < p1; ++a) {
                int key = eid[a];
                int b = a - 1;
                while (b >= p0 && eid[b] > key) { eid[b + 1] = eid[b]; --b; }
                eid[b + 1] = key;
            }
            float dg = 0.f;
            for (int p = p0; p < p1; ++p) dg += ea[eid[p]];
            dis[node] = dg > 0.f ? rsqrtf(fmaxf(dg, EPSV)) : 0.f;
        }
    }
}

// pack (src_row, norm_weight) into int2 so agg does one 8B load per edge
__global__ void fill_csr(const int* __restrict__ eid, const int* __restrict__ row,
                         const int* __restrict__ col, const float* __restrict__ ea,
                         const float* __restrict__ dis, int2* __restrict__ csr, int E_) {
    int p = blockIdx.x * blockDim.x + threadIdx.x;
    if (p >= E_) return;
    int e = eid[p];
    int r = row[e], c = col[e];
    float w = dis[r] * ea[e] * dis[c];
    csr[p] = make_int2(r, __float_as_int(w));
}

// ---------------- batch norm (deterministic partials) ----------------
// 256 threads = 8 rows x 32 lanes (float4 each); LDS tree; block partials
// written TRANSPOSED (pS[d*NB + block]) so bn_reduce reads coalesced.

template <bool GATHER>
__global__ __launch_bounds__(256) void bn_stats(const float* __restrict__ src,
                                                const int* __restrict__ idx,
                                                float* __restrict__ pS,
                                                float* __restrict__ pQ, int n, int NB) {
    int sub = threadIdx.x >> 5;
    int q = threadIdx.x & 31;
    float4 s = make_float4(0, 0, 0, 0), s2 = make_float4(0, 0, 0, 0);
    for (int i = blockIdx.x * 8 + sub; i < n; i += gridDim.x * 8) {
        int r = GATHER ? idx[i] : i;
        float4 v = *(const float4*)&src[(long)r * D + q * 4];
        s.x += v.x; s.y += v.y; s.z += v.z; s.w += v.w;
        s2.x += v.x * v.x; s2.y += v.y * v.y; s2.z += v.z * v.z; s2.w += v.w * v.w;
    }
    __shared__ float4 redA[256], redB[256];
    redA[threadIdx.x] = s;
    redB[threadIdx.x] = s2;
    __syncthreads();
    for (int off = 128; off >= 32; off >>= 1) {
        if (threadIdx.x < off) {
            float4 a = redA[threadIdx.x + off], b = redB[threadIdx.x + off];
            redA[threadIdx.x].x += a.x; redA[threadIdx.x].y += a.y;
            redA[threadIdx.x].z += a.z; redA[threadIdx.x].w += a.w;
            redB[threadIdx.x].x += b.x; redB[threadIdx.x].y += b.y;
            redB[threadIdx.x].z += b.z; redB[threadIdx.x].w += b.w;
        }
        __syncthreads();
    }
    if (threadIdx.x < 32) {
        float4 a = redA[threadIdx.x], b = redB[threadIdx.x];
        int bofs = blockIdx.x;
        pS[(q * 4 + 0) * NB + bofs] = a.x;
        pS[(q * 4 + 1) * NB + bofs] = a.y;
        pS[(q * 4 + 2) * NB + bofs] = a.z;
        pS[(q * 4 + 3) * NB + bofs] = a.w;
        pQ[(q * 4 + 0) * NB + bofs] = b.x;
        pQ[(q * 4 + 1) * NB + bofs] = b.y;
        pQ[(q * 4 + 2) * NB + bofs] = b.z;
        pQ[(q * 4 + 3) * NB + bofs] = b.w;
    }
}

// one block per feature d; coalesced reads of pS[d*NB..], LDS tree reduce.
__global__ __launch_bounds__(256) void bn_reduce(const float* __restrict__ pS,
                                                 const float* __restrict__ pQ, int nb,
                                                 const float* __restrict__ gamma,
                                                 const float* __restrict__ beta,
                                                 float* __restrict__ scale,
                                                 float* __restrict__ shift, float n) {
    int d = blockIdx.x;
    int tid = threadIdx.x;
    float s = 0.f, q = 0.f;
    for (int b = tid; b < nb; b += 256) {
        s += pS[d * nb + b];
        q += pQ[d * nb + b];
    }
    __shared__ float smS[256], smQ[256];
    smS[tid] = s;
    smQ[tid] = q;
    __syncthreads();
    for (int off = 128; off > 0; off >>= 1) {
        if (tid < off) {
            smS[tid] += smS[tid + off];
            smQ[tid] += smQ[tid + off];
        }
        __syncthreads();
    }
    if (tid == 0) {
        float mean = smS[0] / n;
        float var = smQ[0] / n - mean * mean;
        float rstd = rsqrtf(var + EPSV);
        float sc = gamma[d] * rstd;
        scale[d] = sc;
        shift[d] = beta[d] - mean * sc;
    }
}

// ---------------- GEMM: h = (src*scale+shift) @ W, output bf16 ----------------
// 64 rows/block, 256 threads = 8 rowgroups x 32 colgroups, 8x4 micro-tile.

template <bool GATHER>
__global__ __launch_bounds__(256) void gemm_bn(const float* __restrict__ src,
                                               const int* __restrict__ idx,
                                               const float* __restrict__ scale,
                                               const float* __restrict__ shift,
                                               const float* __restrict__ W,
                                               unsigned short* __restrict__ outb, int n) {
    __shared__ float xs[64 * 132];  // 33.8 KB
    int tid = threadIdx.x;
    int r0 = blockIdx.x * 64;
    const float4* scale4 = (const float4*)scale;
    const float4* shift4 = (const float4*)shift;
    for (int it = 0; it < 8; ++it) {
        int flat = it * 256 + tid;  // 0..2047
        int r = flat >> 5;          // 0..63
        int kq = flat & 31;         // float4 index along k
        int gr = r0 + r;
        float4 v = make_float4(0.f, 0.f, 0.f, 0.f);
        if (gr < n) {
            int srow = GATHER ? idx[gr] : gr;
            float4 x4 = *(const float4*)&src[(long)srow * D + kq * 4];
            float4 sc = scale4[kq], sh = shift4[kq];
            v = make_float4(x4.x * sc.x + sh.x, x4.y * sc.y + sh.y, x4.z * sc.z + sh.z,
                            x4.w * sc.w + sh.w);
        }
        *(float4*)&xs[r * 132 + kq * 4] = v;
    }
    __syncthreads();
    int cg = tid & 31;  // cols cg*4..cg*4+3
    int rg = tid >> 5;  // rows rg*8..rg*8+7
    float acc[8][4];
#pragma unroll
    for (int j = 0; j < 8; ++j)
#pragma unroll
        for (int q = 0; q < 4; ++q) acc[j][q] = 0.f;
    const float4* Wv = (const float4*)W;
#pragma unroll 8
    for (int k = 0; k < 128; ++k) {
        float4 wv = Wv[k * 32 + cg];
        float xr[8];
#pragma unroll
        for (int j = 0; j < 8; ++j) xr[j] = xs[(rg * 8 + j) * 132 + k];
#pragma unroll
        for (int j = 0; j < 8; ++j) {
            acc[j][0] += xr[j] * wv.x;
            acc[j][1] += xr[j] * wv.y;
            acc[j][2] += xr[j] * wv.z;
            acc[j][3] += xr[j] * wv.w;
        }
    }
#pragma unroll
    for (int j = 0; j < 8; ++j) {
        int gr = r0 + rg * 8 + j;
        if (gr < n) {
            ushort4 o = make_ushort4(f2bf(acc[j][0]), f2bf(acc[j][1]), f2bf(acc[j][2]),
                                     f2bf(acc[j][3]));
            *(ushort4*)&outb[(long)gr * D + cg * 4] = o;
        }
    }
}

// ---------------- aggregation: x[i] = relu(b + sum_e w_e * h[row_e]) ----------------
// h is bf16 (256B rows): 1 node per wave, lane d holds features 2d,2d+1
// (one dword gather per edge per lane); fp32 accumulate; 8-edge unroll.

__global__ __launch_bounds__(256) void agg_kernel(const unsigned int* __restrict__ hw,
                                                  const int2* __restrict__ csr,
                                                  const int* __restrict__ offs,
                                                  const float2* __restrict__ bias2,
                                                  float2* __restrict__ xout, int n) {
    int node = blockIdx.x * 4 + (threadIdx.x >> 6);
    int d = threadIdx.x & 63;
    if (node >= n) return;
    int p0 = offs[node], p1 = offs[node + 1];
    float2 acc = bias2[d];
    int p = p0;
    for (; p + 8 <= p1; p += 8) {
        int2 e0 = csr[p], e1 = csr[p + 1], e2 = csr[p + 2], e3 = csr[p + 3];
        int2 e4 = csr[p + 4], e5 = csr[p + 5], e6 = csr[p + 6], e7 = csr[p + 7];
        unsigned int u0 = hw[(long)e0.x * 64 + d];
        unsigned int u1 = hw[(long)e1.x * 64 + d];
        unsigned int u2 = hw[(long)e2.x * 64 + d];
        unsigned int u3 = hw[(long)e3.x * 64 + d];
        unsigned int u4 = hw[(long)e4.x * 64 + d];
        unsigned int u5 = hw[(long)e5.x * 64 + d];
        unsigned int u6 = hw[(long)e6.x * 64 + d];
        unsigned int u7 = hw[(long)e7.x * 64 + d];
        float w0 = __int_as_float(e0.y), w1 = __int_as_float(e1.y);
        float w2 = __int_as_float(e2.y), w3 = __int_as_float(e3.y);
        float w4 = __int_as_float(e4.y), w5 = __int_as_float(e5.y);
        float w6 = __int_as_float(e6.y), w7 = __int_as_float(e7.y);
        acc.x += w0 * __uint_as_float(u0 << 16); acc.y += w0 * __uint_as_float(u0 & 0xffff0000u);
        acc.x += w1 * __uint_as_float(u1 << 16); acc.y += w1 * __uint_as_float(u1 & 0xffff0000u);
        acc.x += w2 * __uint_as_float(u2 << 16); acc.y += w2 * __uint_as_float(u2 & 0xffff0000u);
        acc.x += w3 * __uint_as_float(u3 << 16); acc.y += w3 * __uint_as_float(u3 & 0xffff0000u);
        acc.x += w4 * __uint_as_float(u4 << 16); acc.y += w4 * __uint_as_float(u4 & 0xffff0000u);
        acc.x += w5 * __uint_as_float(u5 << 16); acc.y += w5 * __uint_as_float(u5 & 0xffff0000u);
        acc.x += w6 * __uint_as_float(u6 << 16); acc.y += w6 * __uint_as_float(u6 & 0xffff0000u);
        acc.x += w7 * __uint_as_float(u7 << 16); acc.y += w7 * __uint_as_float(u7 & 0xffff0000u);
    }
    for (; p < p1; ++p) {
        int2 e = csr[p];
        unsigned int u = hw[(long)e.x * 64 + d];
        float w = __int_as_float(e.y);
        acc.x += w * __uint_as_float(u << 16);
        acc.y += w * __uint_as_float(u & 0xffff0000u);
    }
    xout[(long)node * 64 + d] = make_float2(fmaxf(acc.x, 0.f), fmaxf(acc.y, 0.f));
}

// ---------------- softmax pooling (segment bounds found in-block) ----------------

__global__ __launch_bounds__(512) void pool_kernel(const float* __restrict__ tfidf,
                                                   const int* __restrict__ batch,
                                                   const float* __restrict__ x,
                                                   float* __restrict__ out, int n) {
    int g = blockIdx.x;
    int tid = threadIdx.x;
    __shared__ int sbounds[2];
    if (tid < 2) {
        int target = g + tid;
        int lo = 0, hi = n;
        while (lo < hi) {
            int mid = (lo + hi) >> 1;
            if (batch[mid] < target) lo = mid + 1;
            else hi = mid;
        }
        sbounds[tid] = lo;
    }
    __syncthreads();
    int s0 = sbounds[0], s1 = sbounds[1];
    int d = tid & 127, sub = tid >> 7;  // 4-way node split
    __shared__ float red[512];
    float m = -1e30f;
    for (int i = s0 + tid; i < s1; i += 512) m = fmaxf(m, tfidf[i]);
    red[tid] = m;
    __syncthreads();
    for (int off = 256; off > 0; off >>= 1) {
        if (tid < off) red[tid] = fmaxf(red[tid], red[tid + off]);
        __syncthreads();
    }
    m = red[0];
    __syncthreads();
    float s = 0.f;
    for (int i = s0 + tid; i < s1; i += 512) s += __expf(tfidf[i] - m);
    red[tid] = s;
    __syncthreads();
    for (int off = 256; off > 0; off >>= 1) {
        if (tid < off) red[tid] += red[tid + off];
        __syncthreads();
    }
    s = red[0];
    __syncthreads();
    float acc = 0.f;
    for (int i = s0 + sub; i < s1; i += 4) acc += __expf(tfidf[i] - m) * x[(long)i * D + d];
    red[tid] = acc;
    __syncthreads();
    if (tid < 128) {
        float a = red[d] + red[128 + d] + red[256 + d] + red[384 + d];
        out[g * D + d] = (s1 > s0) ? a / s : 0.f;
    }
}

// ---------------- launch ----------------

extern "C" void kernel_launch(void* const* d_in, const int* in_sizes, int n_in, void* d_out,
                              int out_size, void* d_ws, size_t ws_size, hipStream_t stream) {
    const int N = in_sizes[0];
    const int E = in_sizes[4];
    const int G = out_size / D;
    const int BN_GRID = 512;

    const int* x_index = (const int*)d_in[0];
    const float* tfidf = (const float*)d_in[1];
    const int* ei_row = (const int*)d_in[2];
    const int* ei_col = ei_row + E;
    const int* batch = (const int*)d_in[3];
    const float* edge_attr = (const float*)d_in[4];
    const float* emb = (const float*)d_in[5];
    const float* gamma1 = (const float*)d_in[6];
    const float* beta1 = (const float*)d_in[7];
    const float* W1 = (const float*)d_in[8];
    const float* b1 = (const float*)d_in[9];
    const float* gamma2 = (const float*)d_in[10];
    const float* beta2 = (const float*)d_in[11];
    const float* W2 = (const float*)d_in[12];
    const float* b2 = (const float*)d_in[13];
    float* out = (float*)d_out;

    // ---- workspace carve (256B aligned) ----
    size_t off = 0;
    char* base = (char*)d_ws;
    auto carve = [&](size_t bytes) -> void* {
        void* p = base + off;
        off = (off + bytes + 255) & ~(size_t)255;
        return p;
    };
    unsigned short* bufA = (unsigned short*)carve((size_t)N * D * 2);  // h (bf16)
    float* bufB = (float*)carve((size_t)N * D * 4);                    // x (layer output)
    int* eid = (int*)carve((size_t)E * 4);                             // CSR edge ids
    int2* csr = (int2*)carve((size_t)E * 8);                           // packed (row, w)
    int* cnt = (int*)carve((size_t)N * 4);                             // zeroed each launch
    float* dis = (float*)carve((size_t)N * 4);
    int* offs = (int*)carve((size_t)(N + 1) * 4);
    int* cursor = (int*)carve((size_t)N * 4);
    int* bsum = (int*)carve(64 * 4);
    float* scale1 = (float*)carve(D * 4);
    float* shift1 = (float*)carve(D * 4);
    float* scale2 = (float*)carve(D * 4);
    float* shift2 = (float*)carve(D * 4);
    float* pS = (float*)carve((size_t)BN_GRID * D * 4);
    float* pQ = (float*)carve((size_t)BN_GRID * D * 4);
    (void)ws_size;
    (void)n_in;

    hipMemsetAsync(cnt, 0, (size_t)N * 4, stream);

    // ---- edge preprocessing: CSR (deterministic; shared by both layers) ----
    hist_kernel<<<cdiv(E, 256), 256, 0, stream>>>(ei_col, cnt, E);
    int nb = cdiv(N, 1024);
    scan_chunk_sums<<<nb, 1024, 0, stream>>>(cnt, bsum, N);
    scan_final<<<nb, 1024, 0, stream>>>(cnt, bsum, nb, offs, cursor, N, E);
    scatter_eid<<<cdiv(E, 256), 256, 0, stream>>>(ei_col, cursor, eid, E);
    sort_deg_kernel<<<cdiv(N, 4), 256, 0, stream>>>(eid, offs, edge_attr, dis, N);
    fill_csr<<<cdiv(E, 256), 256, 0, stream>>>(eid, ei_row, ei_col, edge_attr, dis, csr, E);

    // ---- layer 1 ----
    bn_stats<true><<<BN_GRID, 256, 0, stream>>>(emb, x_index, pS, pQ, N, BN_GRID);
    bn_reduce<<<D, 256, 0, stream>>>(pS, pQ, BN_GRID, gamma1, beta1, scale1, shift1, (float)N);
    gemm_bn<true><<<cdiv(N, 64), 256, 0, stream>>>(emb, x_index, scale1, shift1, W1, bufA, N);
    agg_kernel<<<cdiv(N, 4), 256, 0, stream>>>((const unsigned int*)bufA, csr, offs,
                                               (const float2*)b1, (float2*)bufB, N);

    // ---- layer 2 ----
    bn_stats<false><<<BN_GRID, 256, 0, stream>>>(bufB, nullptr, pS, pQ, N, BN_GRID);
    bn_reduce<<<D, 256, 0, stream>>>(pS, pQ, BN_GRID, gamma2, beta2, scale2, shift2, (float)N);
    gemm_bn<false><<<cdiv(N, 64), 256, 0, stream>>>(bufB, nullptr, scale2, shift2, W2, bufA, N);
    agg_kernel<<<cdiv(N, 4), 256, 0, stream>>>((const unsigned int*)bufA, csr, offs,
                                               (const float2*)b2, (float2*)bufB, N);

    // ---- softmax pooling (bounds fused into pool) ----
    pool_kernel<<<G, 512, 0, stream>>>(tfidf, batch, bufB, out, N);
}